// Round 9
// baseline (446.380 us; speedup 1.0000x reference)
//
#include <hip/hip_runtime.h>
#include <hip/hip_bf16.h>

// Problem constants
#define BB   2
#define NN   50000
#define BN   100000     // B*N
#define NE   500000
#define NSB  196        // scan blocks = ceil(NN/256)
#define NODE_NB 1563    // ceil(BN/64)

using u16 = unsigned short;
using u32 = unsigned int;
typedef __attribute__((ext_vector_type(8))) short short8;      // 8 x bf16/f16 bits
typedef __attribute__((ext_vector_type(8))) _Float16 half8;    // 8 x f16 (4 VGPRs)
typedef __attribute__((ext_vector_type(4))) float f32x4;       // MFMA accumulator

__device__ __forceinline__ u16 f2bf(float f) {   // RNE f32 -> bf16 (finite inputs)
    union { float f; u32 u; } w; w.f = f;
    return (u16)((w.u + 0x7fffu + ((w.u >> 16) & 1u)) >> 16);
}
__device__ __forceinline__ u16 f2h(float f) {    // RNE f32 -> f16
    _Float16 h = (_Float16)f; u16 u; __builtin_memcpy(&u, &h, 2); return u;
}

#if defined(__has_builtin)
#if __has_builtin(__builtin_amdgcn_cvt_pk_bf16_f32)
#define HAVE_CVTPK 1
#endif
#if __has_builtin(__builtin_amdgcn_cvt_pkrtz)
#define HAVE_PKRTZ 1
#endif
#endif

__device__ __forceinline__ u32 pack_bf(float lo, float hi) {
#ifdef HAVE_CVTPK
    auto r = __builtin_amdgcn_cvt_pk_bf16_f32(lo, hi);
    u32 out; __builtin_memcpy(&out, &r, sizeof(out));
    return out;
#else
    return ((u32)f2bf(hi) << 16) | (u32)f2bf(lo);
#endif
}

__device__ __forceinline__ u32 pack_h2(float lo, float hi) {
#ifdef HAVE_PKRTZ
    auto r = __builtin_amdgcn_cvt_pkrtz(lo, hi);
    u32 out; __builtin_memcpy(&out, &r, sizeof(out));
    return out;
#else
    return ((u32)f2h(hi) << 16) | (u32)f2h(lo);
#endif
}

__device__ __forceinline__ u32 pk_add_h2(u32 a, u32 b) {
    u32 d; asm("v_pk_add_f16 %0, %1, %2" : "=v"(d) : "v"(a), "v"(b)); return d;
}
__device__ __forceinline__ u32 pk_relu_h2(u32 a) {
    u32 d, z = 0u;
    asm("v_pk_max_f16 %0, %1, %2" : "=v"(d) : "v"(a), "v"(z)); return d;
}
__device__ __forceinline__ half8 as_h8(short8 s) {
    half8 h; __builtin_memcpy(&h, &s, 16); return h;
}

// ---------------------------------------------------------------------------
// Weight prep (blocks 0..320) fused with CSR histogram (blocks 321..).
// frag regions (u16): w1e @0 ([16][4][64][8] bf16), w1n @32768 ([16][2][64][8]),
//                     w2e' @49152 ([4][8][64][8] f16), w2n' @65536 (bf16).
// ---------------------------------------------------------------------------
__global__ __launch_bounds__(256) void weight_prep_hist(
    const float* __restrict__ ew1, const float* __restrict__ nw1,
    const float* __restrict__ ew2, const float* __restrict__ nw2,
    const float* __restrict__ dw,  const float* __restrict__ db,
    const float* __restrict__ eb2, const float* __restrict__ nb2,
    const int* __restrict__ edges, int* __restrict__ curU, int* __restrict__ curV,
    u16* __restrict__ frag, float* __restrict__ bias2)
{
    int blk = blockIdx.x, t = threadIdx.x;
    if (blk >= 321) {                       // CSR histogram (independent work)
        int e = (blk - 321) * 256 + t;
        if (e < NE) {
            atomicAdd(&curU[edges[2*e]], 1);
            atomicAdd(&curV[edges[2*e+1]], 1);
        }
        return;
    }
    if (blk < 192) {
        int idx = blk * 256 + t;                 // 0..49151
        const float* src; int KB, local;
        if (idx < 32768) { local = idx;         src = ew1; KB = 4; }
        else             { local = idx - 32768; src = nw1; KB = 2; }
        int j = local & 7, l = (local >> 3) & 63, rest = local >> 9;
        int kblk = rest % KB, ntile = rest / KB;
        int n = ntile * 16 + (l & 15);
        int k = kblk * 32 + ((l >> 4) << 3) + j;
        frag[idx] = f2bf(src[k * 256 + n]);
    } else if (blk < 320) {
        int idx = (blk - 192) * 256 + t;         // 0..32767
        bool is_e = (idx < 16384);
        const float* src = is_e ? ew2 : nw2;
        int local = idx & 16383;
        int j = local & 7, l = (local >> 3) & 63, rest = local >> 9;
        int kblk = rest & 7, ntile = rest >> 3;
        int n = ntile * 16 + (l & 15);
        int k = kblk * 32 + ((l >> 4) << 3) + j;
        float s = 0.f;
        for (int jj = 0; jj < 128; ++jj) s = fmaf(src[k * 128 + jj], dw[jj * 64 + n], s);
        frag[49152 + idx] = is_e ? f2h(s) : f2bf(s);
    } else if (t < 128) {
        int d = t & 63;
        const float* bsrc = (t >= 64) ? nb2 : eb2;
        float s = 0.f;
        #pragma unroll 4
        for (int j = 0; j < 128; ++j) s = fmaf(bsrc[j], dw[j * 64 + d], s);
        if (t >= 64) bias2[64 + d] = s + db[d];
        else         bias2[d] = s;
    }
}

// ---------------------------------------------------------------------------
// scan passes 2/3 (y = 0 -> U, y = 1 -> V)
// ---------------------------------------------------------------------------
__global__ __launch_bounds__(256) void scan_pass2d(const int* __restrict__ bsum2,
                                                   int* __restrict__ boff2) {
    __shared__ int s[256];
    const int t = threadIdx.x;
    const int base = blockIdx.y * (NSB + 1);
    s[t] = (t < NSB) ? bsum2[base + t] : 0;
    __syncthreads();
    for (int d = 1; d < 256; d <<= 1) {
        int v = (t >= d) ? s[t - d] : 0;
        __syncthreads();
        s[t] += v;
        __syncthreads();
    }
    if (t <= NSB) boff2[base + t] = (t == 0) ? 0 : s[t - 1];
}

__global__ __launch_bounds__(256) void scan_pass3d(int* __restrict__ curU,
                                                   int* __restrict__ curV,
                                                   const int* __restrict__ boff2,
                                                   int* __restrict__ uoff,
                                                   int* __restrict__ voff) {
    __shared__ int s[256];
    const int t = threadIdx.x;
    int* cursor = blockIdx.y ? curV : curU;
    int* off    = blockIdx.y ? voff : uoff;
    const int base = blockIdx.y * (NSB + 1);
    int i = blockIdx.x * 256 + t;
    int v = (i < NN) ? cursor[i] : 0;
    s[t] = v;
    __syncthreads();
    for (int d = 1; d < 256; d <<= 1) {
        int p = (t >= d) ? s[t - d] : 0;
        __syncthreads();
        s[t] += p;
        __syncthreads();
    }
    int excl = boff2[base + blockIdx.x] + s[t] - v;
    if (i < NN) { off[i] = excl; cursor[i] = excl; }
    if (i == NN - 1) off[NN] = excl + v;
}

// ---------------------------------------------------------------------------
// Fused CSR fill: u-slot (uv row + slot id) and v-slot (vmap -> u-slot).
// ---------------------------------------------------------------------------
__global__ __launch_bounds__(256) void csr_fill2(const int* __restrict__ edges,
                                                 int* __restrict__ curU,
                                                 int* __restrict__ curV,
                                                 int2* __restrict__ uv,
                                                 int* __restrict__ vmap) {
    int e = blockIdx.x * 256 + threadIdx.x;
    if (e < NE) {
        int u = edges[2*e], v = edges[2*e+1];
        int s0 = atomicAdd(&curU[u], 1);
        uv[s0] = make_int2(u, v);
        int s1 = atomicAdd(&curV[v], 1);
        vmap[s1] = s0;
    }
}

// ---------------------------------------------------------------------------
// Node MLP (dw-fused) + edge-MLP per-node halves At/Ab for ALL BN rows.
// 24 KB LDS; hidden dim processed in two 128-wide halves. Also absorbs
// scan_pass1 (blocks >= NODE_NB).
// ---------------------------------------------------------------------------
__global__ __launch_bounds__(256) void node_mlp_kernel(
    const float* __restrict__ x, const float* __restrict__ nb1,
    const float* __restrict__ eb1, const float* __restrict__ bias2,
    const u16* __restrict__ frag,
    u16* __restrict__ At, u16* __restrict__ Ab, float* __restrict__ out,
    const int* __restrict__ curU, const int* __restrict__ curV,
    int* __restrict__ bsum2)
{
    __shared__ u16 xs[64 * 64];     // 8 KB, 8 chunks/row, swizzle mask 7
    __shared__ u16 hid[64 * 128];   // 16 KB, 16 chunks/row, swizzle mask 15
    const int t = threadIdx.x;

    if (blockIdx.x >= NODE_NB) {    // fused scan_pass1 for U and V histograms
        int sb = blockIdx.x - NODE_NB;       // 0..2*NSB-1
        int y = sb / NSB, xi = sb - y * NSB;
        const int* cursor = y ? curV : curU;
        int* s = (int*)xs;
        int i = xi * 256 + t;
        s[t] = (i < NN) ? cursor[i] : 0;
        __syncthreads();
        for (int d = 128; d > 0; d >>= 1) {
            if (t < d) s[t] += s[t + d];
            __syncthreads();
        }
        if (t == 0) bsum2[y * (NSB + 1) + xi] = s[0];
        return;
    }

    const int wave = t >> 6, l = t & 63, lane15 = l & 15, quad = l >> 4;
    const int r0 = blockIdx.x * 64;
    const int valid = min(64, BN - r0);

    // stage + convert x -> xs (bf16)
    #pragma unroll
    for (int it = 0; it < 4; ++it) {
        int i = t + it * 256;          // 0..1023
        int m = i >> 4, c4 = i & 15;   // row, float4-col (8B half-chunk)
        int row = min(r0 + m, BN - 1);
        float4 g = ((const float4*)x)[(size_t)row * 16 + c4];
        uint2 q = make_uint2(pack_bf(g.x, g.y), pack_bf(g.z, g.w));
        int chunk = c4 >> 1;
        *(uint2*)(xs + m * 64 + ((chunk ^ (m & 7)) << 3) + (c4 & 1) * 4) = q;
    }
    __syncthreads();

    // Node MLP: GEMM1 in two hidden halves, GEMM2 accumulates across halves.
    f32x4 acc2[4];
    #pragma unroll
    for (int mt = 0; mt < 4; ++mt) acc2[mt] = f32x4{0.f,0.f,0.f,0.f};
    const u16* w1n = frag + 32768;   // [16 ntile][2 kblk][64][8]
    const u16* w2n = frag + 65536;   // [4 ntile][8 kblk][64][8]
    #pragma unroll
    for (int H = 0; H < 2; ++H) {
        f32x4 acc1[2][4];
        #pragma unroll
        for (int i = 0; i < 2; ++i)
            #pragma unroll
            for (int mt = 0; mt < 4; ++mt) acc1[i][mt] = f32x4{0.f,0.f,0.f,0.f};
        #pragma unroll
        for (int kblk = 0; kblk < 2; ++kblk) {
            short8 bf[4], af[2];
            int chunk = kblk * 4 + quad;
            #pragma unroll
            for (int mt = 0; mt < 4; ++mt) {
                int row = mt*16 + lane15;
                bf[mt] = *(const short8*)(xs + row * 64 + ((chunk ^ (row & 7)) << 3));
            }
            #pragma unroll
            for (int i = 0; i < 2; ++i)
                af[i] = *(const short8*)(w1n + (((H*8 + wave*2 + i)*2 + kblk)*64 + l) * 8);
            #pragma unroll
            for (int i = 0; i < 2; ++i)
                #pragma unroll
                for (int mt = 0; mt < 4; ++mt)
                    acc1[i][mt] = __builtin_amdgcn_mfma_f32_16x16x32_bf16(af[i], bf[mt], acc1[i][mt], 0, 0, 0);
        }
        // epilogue: relu+bias -> bf16 hid half (cols [H*128, H*128+128))
        #pragma unroll
        for (int i = 0; i < 2; ++i) {
            int ntl = wave*2 + i;                  // local col-tile 0..7
            int n0 = (H*8 + ntl)*16 + quad*4;      // global hidden col
            int c16 = ntl*2 + (quad >> 1);         // local 16B chunk 0..15
            float4 bv = *(const float4*)(nb1 + n0);
            #pragma unroll
            for (int mt = 0; mt < 4; ++mt) {
                int row = mt*16 + lane15;
                uint2 q = make_uint2(
                    pack_bf(fmaxf(acc1[i][mt][0] + bv.x, 0.f), fmaxf(acc1[i][mt][1] + bv.y, 0.f)),
                    pack_bf(fmaxf(acc1[i][mt][2] + bv.z, 0.f), fmaxf(acc1[i][mt][3] + bv.w, 0.f)));
                *(uint2*)(hid + row * 128 + ((c16 ^ (row & 15)) << 3) + (quad & 1) * 4) = q;
            }
        }
        __syncthreads();
        // GEMM2 partial over this K-half
        #pragma unroll
        for (int kb = 0; kb < 4; ++kb) {
            short8 bf[4], af;
            int chunk = kb * 4 + quad;
            #pragma unroll
            for (int mt = 0; mt < 4; ++mt) {
                int row = mt*16 + lane15;
                bf[mt] = *(const short8*)(hid + row * 128 + ((chunk ^ (row & 15)) << 3));
            }
            af = *(const short8*)(w2n + ((wave*8 + H*4 + kb)*64 + l) * 8);
            #pragma unroll
            for (int mt = 0; mt < 4; ++mt)
                acc2[mt] = __builtin_amdgcn_mfma_f32_16x16x32_bf16(af, bf[mt], acc2[mt], 0, 0, 0);
        }
        __syncthreads();   // hid reusable (next half / edge phase)
    }
    {   // node output store (f32)
        int n0 = wave*16 + quad*4;
        float4 bv = *(const float4*)(bias2 + 64 + n0);
        #pragma unroll
        for (int mt = 0; mt < 4; ++mt) {
            int m = mt*16 + lane15;
            if (m < valid) {
                float4 o;
                o.x = acc2[mt][0] + bv.x; o.y = acc2[mt][1] + bv.y;
                o.z = acc2[mt][2] + bv.z; o.w = acc2[mt][3] + bv.w;
                *(float4*)(out + (size_t)(r0 + m) * 64 + n0) = o;
            }
        }
    }

    // Edge per-node halves: T=0 -> At (+eb1), T=1 -> Ab; each in 2 hidden halves.
    const u16* w1e = frag;   // [16 ntile][4 kblk][64][8]; kblk 0-1 = top, 2-3 = bot
    #pragma unroll
    for (int T = 0; T < 2; ++T) {
        u16* dst = T ? Ab : At;
        #pragma unroll
        for (int H = 0; H < 2; ++H) {
            f32x4 acc[2][4];
            #pragma unroll
            for (int i = 0; i < 2; ++i)
                #pragma unroll
                for (int mt = 0; mt < 4; ++mt) acc[i][mt] = f32x4{0.f,0.f,0.f,0.f};
            #pragma unroll
            for (int kblk = 0; kblk < 2; ++kblk) {
                short8 bf[4], af[2];
                int chunk = kblk * 4 + quad;
                #pragma unroll
                for (int mt = 0; mt < 4; ++mt) {
                    int row = mt*16 + lane15;
                    bf[mt] = *(const short8*)(xs + row * 64 + ((chunk ^ (row & 7)) << 3));
                }
                #pragma unroll
                for (int i = 0; i < 2; ++i)
                    af[i] = *(const short8*)(w1e + (((H*8 + wave*2 + i)*4 + T*2 + kblk)*64 + l) * 8);
                #pragma unroll
                for (int i = 0; i < 2; ++i)
                    #pragma unroll
                    for (int mt = 0; mt < 4; ++mt)
                        acc[i][mt] = __builtin_amdgcn_mfma_f32_16x16x32_bf16(af[i], bf[mt], acc[i][mt], 0, 0, 0);
            }
            // epilogue -> f16 hid half
            #pragma unroll
            for (int i = 0; i < 2; ++i) {
                int ntl = wave*2 + i;
                int n0 = (H*8 + ntl)*16 + quad*4;
                int c16 = ntl*2 + (quad >> 1);
                float4 bv;
                if (T == 0) bv = *(const float4*)(eb1 + n0);
                else        bv = make_float4(0.f, 0.f, 0.f, 0.f);
                #pragma unroll
                for (int mt = 0; mt < 4; ++mt) {
                    int row = mt*16 + lane15;
                    uint2 q = make_uint2(
                        pack_h2(acc[i][mt][0] + bv.x, acc[i][mt][1] + bv.y),
                        pack_h2(acc[i][mt][2] + bv.z, acc[i][mt][3] + bv.w));
                    *(uint2*)(hid + row * 128 + ((c16 ^ (row & 15)) << 3) + (quad & 1) * 4) = q;
                }
            }
            __syncthreads();
            // store half-rows (256B contiguous per row)
            #pragma unroll
            for (int it = 0; it < 4; ++it) {
                int i = t + it * 256;          // 0..1023
                int m = i >> 4, c = i & 15;
                if (m < valid)
                    ((uint4*)dst)[((size_t)(r0 + m)) * 32 + H*16 + c] =
                        *(const uint4*)(hid + m * 128 + ((c ^ (m & 15)) << 3));
            }
            __syncthreads();   // hid reuse next (T,H)
        }
    }
}

// ---------------------------------------------------------------------------
// Edge combine + GEMM2, BARRIER-FREE: each wave owns 16 u-sorted edges
// end-to-end in its private LDS quadrant. No __syncthreads anywhere -> the
// compiler's counted-vmcnt scheduling keeps the next phase's At/Ab gather
// in flight under the current phase's MFMA (true reg double-buffering).
// Phases p=0..3 = (batch b = p>>1, K-half = p&1). One 256B interleaved perm
// row per edge ([batch0 128B][batch1 128B]).
// ---------------------------------------------------------------------------
__global__ __launch_bounds__(256) void edge_emb4_kernel(
    const u16* __restrict__ At, const u16* __restrict__ Ab,
    const int2* __restrict__ uv, const float* __restrict__ bias2,
    const u16* __restrict__ frag, u16* __restrict__ perm)
{
    __shared__ u16 hid[64 * 128];   // 16 KB; wave quadrant = rows [wave*16,+16)
    const int t = threadIdx.x;
    const int wave = t >> 6, l = t & 63, lane15 = l & 15, quad = l >> 4;
    const int e0w = blockIdx.x * 64 + wave * 16;
    const int evalid = min(16, NE - e0w);          // may be <= 0 (tail waves)

    // this lane's combine row = lane15; its edge's At/Ab row bases
    int2 puv = uv[min(e0w + lane15, NE - 1)];
    const u32 ubase = (u32)puv.x * 32;             // uint4 index of At row
    const u32 vbase = (u32)puv.y * 32;
    u16* hw = hid + wave * 16 * 128;               // quadrant base

    const uint4* atp0 = (const uint4*)At;
    const uint4* atp1 = (const uint4*)(At + (size_t)NN * 256);
    const uint4* abp0 = (const uint4*)Ab;
    const uint4* abp1 = (const uint4*)(Ab + (size_t)NN * 256);

    const u16* w2 = frag + 49152;   // [4 ntile][8 kblk][64][8] f16
    f32x4 acc[2][4];
    #pragma unroll
    for (int b = 0; b < 2; ++b)
        #pragma unroll
        for (int ntl = 0; ntl < 4; ++ntl) acc[b][ntl] = f32x4{0.f,0.f,0.f,0.f};

    uint4 paA[4], pbA[4], paB[4], pbB[4];

    // prologue: phase 0 (b=0, half=0) gather -> buffer A
    #pragma unroll
    for (int it = 0; it < 4; ++it) {
        paA[it] = atp0[ubase + quad + 4*it];
        pbA[it] = abp0[vbase + quad + 4*it];
    }

    // PHASE(b, half, CUR, NXT-prefetch) — prefetch issued FIRST so it stays
    // in flight under this phase's combine + MFMA (no barrier to drain it).
#define EDGE_PHASE(BB_, HH_, CA, CB, DO_PRE, NA, NB, PAT, PAB, PH_)          \
    {                                                                         \
        if (DO_PRE) {                                                         \
            _Pragma("unroll")                                                 \
            for (int it = 0; it < 4; ++it) {                                  \
                NA[it] = PAT[ubase + (PH_)*16 + quad + 4*it];                 \
                NB[it] = PAB[vbase + (PH_)*16 + quad + 4*it];                 \
            }                                                                 \
        }                                                                     \
        _Pragma("unroll")                                                     \
        for (int it = 0; it < 4; ++it) {                                      \
            uint4 r;                                                          \
            r.x = pk_relu_h2(pk_add_h2(CA[it].x, CB[it].x));                  \
            r.y = pk_relu_h2(pk_add_h2(CA[it].y, CB[it].y));                  \
            r.z = pk_relu_h2(pk_add_h2(CA[it].z, CB[it].z));                  \
            r.w = pk_relu_h2(pk_add_h2(CA[it].w, CB[it].w));                  \
            int c = quad + 4*it;                                              \
            *(uint4*)(hw + lane15 * 128 + ((c ^ lane15) << 3)) = r;           \
        }                                                                     \
        _Pragma("unroll")                                                     \
        for (int kb = 0; kb < 4; ++kb) {                                      \
            short8 bf = *(const short8*)(hw + lane15 * 128 +                  \
                                         (((kb*4 + quad) ^ lane15) << 3));    \
            _Pragma("unroll")                                                 \
            for (int ntl = 0; ntl < 4; ++ntl) {                               \
                short8 af = *(const short8*)(w2 + ((ntl*8 + (HH_)*4 + kb)*64 + l) * 8); \
                acc[BB_][ntl] = __builtin_amdgcn_mfma_f32_16x16x32_f16(       \
                    as_h8(af), as_h8(bf), acc[BB_][ntl], 0, 0, 0);            \
            }                                                                 \
        }                                                                     \
    }

    EDGE_PHASE(0, 0, paA, pbA, 1, paB, pbB, atp0, abp0, 1)   // pre: (b0,h1)
    EDGE_PHASE(0, 1, paB, pbB, 1, paA, pbA, atp1, abp1, 0)   // pre: (b1,h0)
    EDGE_PHASE(1, 0, paA, pbA, 1, paB, pbB, atp1, abp1, 1)   // pre: (b1,h1)
    EDGE_PHASE(1, 1, paB, pbB, 0, paA, pbA, atp0, abp0, 0)   // no prefetch
#undef EDGE_PHASE

    {   // epilogue: both batches' bf16 rows into quadrant (16 chunks/row)
        int n0 = quad * 4;
        #pragma unroll
        for (int ntl = 0; ntl < 4; ++ntl) {
            float4 bv = *(const float4*)(bias2 + ntl*16 + n0);
            #pragma unroll
            for (int b = 0; b < 2; ++b) {
                int cc = b*8 + ntl*2 + (quad >> 1);   // 16B chunk 0..15
                uint2 q = make_uint2(
                    pack_bf(acc[b][ntl][0] + bv.x, acc[b][ntl][1] + bv.y),
                    pack_bf(acc[b][ntl][2] + bv.z, acc[b][ntl][3] + bv.w));
                *(uint2*)(hw + lane15 * 128 + ((cc ^ lane15) << 3) + (quad & 1) * 4) = q;
            }
        }
    }

    // store: 16 rows x 256B, 1KB contiguous per it (same wave, no barrier)
    #pragma unroll
    for (int it = 0; it < 4; ++it) {
        int row = it * 4 + quad;
        int c = lane15;
        if (row < evalid)
            ((uint4*)perm)[((size_t)(e0w + row)) * 16 + c] =
                *(const uint4*)(hw + row * 128 + ((c ^ row) << 3));
    }
}

// ---------------------------------------------------------------------------
// FUSED gather: perm rows are 256B = [batch0 128B][batch1 128B]. One pass
// accumulates both batches for node n (u-run contiguous + v-list indirect).
// ---------------------------------------------------------------------------
#define ACCUM8(q) { union { u32 u; float f; } xx;                         \
    xx.u = (q).x << 16;          a0 += xx.f;                              \
    xx.u = (q).x & 0xffff0000u;  a1 += xx.f;                              \
    xx.u = (q).y << 16;          a2 += xx.f;                              \
    xx.u = (q).y & 0xffff0000u;  a3 += xx.f;                              \
    xx.u = (q).z << 16;          a4 += xx.f;                              \
    xx.u = (q).z & 0xffff0000u;  a5 += xx.f;                              \
    xx.u = (q).w << 16;          a6 += xx.f;                              \
    xx.u = (q).w & 0xffff0000u;  a7 += xx.f; }

__global__ __launch_bounds__(256) void gather4_kernel(
    const u32* __restrict__ perm32, const int* __restrict__ uoff,
    const int* __restrict__ voff, const int* __restrict__ vmap,
    float* __restrict__ out)
{
    const int t = threadIdx.x, wave = t >> 6, l = t & 63;
    const int n = blockIdx.x * 4 + wave;
    const int ub = uoff[n], ucnt = uoff[n + 1] - ub;
    const int vb = voff[n], vcnt = voff[n + 1] - vb;
    if ((ucnt | vcnt) == 0) return;
    const int sg = l >> 4, c16 = l & 15;   // 4 slots/group, 16B col in 256B row
    float a0=0.f,a1=0.f,a2=0.f,a3=0.f,a4=0.f,a5=0.f,a6=0.f,a7=0.f;

    for (int j0 = 0; j0 < ucnt; j0 += 8) {
        int jA = j0 + sg, jB = j0 + 4 + sg;
        uint4 qA = *(const uint4*)(perm32 + (size_t)(ub + min(jA, ucnt - 1)) * 64 + c16 * 4);
        uint4 qB = *(const uint4*)(perm32 + (size_t)(ub + min(jB, ucnt - 1)) * 64 + c16 * 4);
        if (jA < ucnt) ACCUM8(qA);
        if (jB < ucnt) ACCUM8(qB);
    }
    for (int j0 = 0; j0 < vcnt; j0 += 8) {
        int jA = j0 + sg, jB = j0 + 4 + sg;
        int pA = vmap[vb + min(jA, vcnt - 1)];
        int pB = vmap[vb + min(jB, vcnt - 1)];
        uint4 qA = *(const uint4*)(perm32 + (size_t)pA * 64 + c16 * 4);
        uint4 qB = *(const uint4*)(perm32 + (size_t)pB * 64 + c16 * 4);
        if (jA < vcnt) ACCUM8(qA);
        if (jB < vcnt) ACCUM8(qB);
    }

    a0 += __shfl_xor(a0, 16); a1 += __shfl_xor(a1, 16);
    a2 += __shfl_xor(a2, 16); a3 += __shfl_xor(a3, 16);
    a4 += __shfl_xor(a4, 16); a5 += __shfl_xor(a5, 16);
    a6 += __shfl_xor(a6, 16); a7 += __shfl_xor(a7, 16);
    a0 += __shfl_xor(a0, 32); a1 += __shfl_xor(a1, 32);
    a2 += __shfl_xor(a2, 32); a3 += __shfl_xor(a3, 32);
    a4 += __shfl_xor(a4, 32); a5 += __shfl_xor(a5, 32);
    a6 += __shfl_xor(a6, 32); a7 += __shfl_xor(a7, 32);

    if (l < 16) {   // lane = c16: 0..7 -> batch0 cols, 8..15 -> batch1 cols
        float* p = out + ((size_t)((l >> 3) * NN + n)) * 64 + (l & 7) * 8;
        float4 h0 = *(float4*)p, h1 = *(float4*)(p + 4);
        h0.x += a0; h0.y += a1; h0.z += a2; h0.w += a3;
        h1.x += a4; h1.y += a5; h1.z += a6; h1.w += a7;
        *(float4*)p = h0; *(float4*)(p + 4) = h1;
    }
}

// ---------------------------------------------------------------------------
extern "C" void kernel_launch(void* const* d_in, const int* in_sizes, int n_in,
                              void* d_out, int out_size, void* d_ws, size_t ws_size,
                              hipStream_t stream) {
    const float* x     = (const float*)d_in[0];
    const int*   edges = (const int*)d_in[1];
    const float* ew1   = (const float*)d_in[2];
    const float* eb1   = (const float*)d_in[3];
    const float* ew2   = (const float*)d_in[4];
    const float* eb2   = (const float*)d_in[5];
    const float* nw1   = (const float*)d_in[6];
    const float* nb1   = (const float*)d_in[7];
    const float* nw2   = (const float*)d_in[8];
    const float* nb2   = (const float*)d_in[9];
    const float* dw    = (const float*)d_in[10];
    const float* db    = (const float*)d_in[11];
    float* out = (float*)d_out;    // [BN][64]

    // Workspace layout (512B aligned)
    char* w = (char*)d_ws;
    size_t o = 0;
    auto take = [&](size_t bytes) { char* p = w + o; o = (o + bytes + 511) & ~(size_t)511; return p; };
    u16*   frag   = (u16*)  take(81920 * 2);                   // 160 KB
    float* bias2  = (float*)take(128 * 4);
    int*   curU   = (int*)  take((size_t)NN * 4);
    int*   curV   = (int*)  take((size_t)NN * 4);
    int*   uoff   = (int*)  take((size_t)(NN + 1) * 4);
    int*   voff   = (int*)  take((size_t)(NN + 1) * 4);
    int*   bsum2  = (int*)  take((size_t)2 * (NSB + 1) * 4);
    int*   boff2  = (int*)  take((size_t)2 * (NSB + 1) * 4);
    int*   vmap   = (int*)  take((size_t)NE * 4);              // 2 MB
    int2*  uv     = (int2*) take((size_t)NE * 8);              // 4 MB
    u16*   At     = (u16*)  take((size_t)BN * 256 * 2);        // 51.2 MB (both batches)
    u16*   Ab     = (u16*)  take((size_t)BN * 256 * 2);        // 51.2 MB
    u16*   perm   = (u16*)  take((size_t)NE * 128 * 2);        // 128 MB (interleaved)
    (void)ws_size;

    // zero histograms (DMA memsets, replaces a dispatch)
    hipMemsetAsync(curU, 0, (size_t)NN * 4, stream);
    hipMemsetAsync(curV, 0, (size_t)NN * 4, stream);

    // weight prep || CSR histogram (independent work, one dispatch)
    weight_prep_hist<<<321 + (NE + 255) / 256, 256, 0, stream>>>(
        ew1, nw1, ew2, nw2, dw, db, eb2, nb2, edges, curU, curV, frag, bias2);

    // node+edge per-node tables || scan_pass1 (both axes)
    node_mlp_kernel<<<NODE_NB + 2 * NSB, 256, 0, stream>>>(
        x, nb1, eb1, bias2, frag, At, Ab, out, curU, curV, bsum2);

    scan_pass2d<<<dim3(1, 2), 256, 0, stream>>>(bsum2, boff2);
    scan_pass3d<<<dim3(NSB, 2), 256, 0, stream>>>(curU, curV, boff2, uoff, voff);
    csr_fill2<<<(NE + 255) / 256, 256, 0, stream>>>(edges, curU, curV, uv, vmap);

    // edge MLP both batches -> interleaved perm rows (barrier-free pipeline)
    edge_emb4_kernel<<<(NE + 63) / 64, 256, 0, stream>>>(At, Ab, uv, bias2, frag, perm);

    // one gather for both batches
    gather4_kernel<<<NN / 4, 256, 0, stream>>>((const u32*)perm, uoff, voff, vmap, out);
}

// Round 14
// 409.933 us; speedup vs baseline: 1.0889x; 1.0889x over previous
//
#include <hip/hip_runtime.h>
#include <hip/hip_bf16.h>

// Problem constants
#define BB   2
#define NN   50000
#define BN   100000     // B*N
#define NE   500000
#define NSB  196        // scan blocks = ceil(NN/256)
#define NODE_NB 1563    // ceil(BN/64)

using u16 = unsigned short;
using u32 = unsigned int;
typedef __attribute__((ext_vector_type(8))) short short8;      // 8 x bf16/f16 bits
typedef __attribute__((ext_vector_type(8))) _Float16 half8;    // 8 x f16 (4 VGPRs)
typedef __attribute__((ext_vector_type(4))) float f32x4;       // MFMA accumulator
typedef __attribute__((ext_vector_type(4))) unsigned int nt4;  // native 16B vector (nt ld/st)

__device__ __forceinline__ u16 f2bf(float f) {   // RNE f32 -> bf16 (finite inputs)
    union { float f; u32 u; } w; w.f = f;
    return (u16)((w.u + 0x7fffu + ((w.u >> 16) & 1u)) >> 16);
}
__device__ __forceinline__ u16 f2h(float f) {    // RNE f32 -> f16
    _Float16 h = (_Float16)f; u16 u; __builtin_memcpy(&u, &h, 2); return u;
}

#if defined(__has_builtin)
#if __has_builtin(__builtin_amdgcn_cvt_pk_bf16_f32)
#define HAVE_CVTPK 1
#endif
#if __has_builtin(__builtin_amdgcn_cvt_pkrtz)
#define HAVE_PKRTZ 1
#endif
#endif

__device__ __forceinline__ u32 pack_bf(float lo, float hi) {
#ifdef HAVE_CVTPK
    auto r = __builtin_amdgcn_cvt_pk_bf16_f32(lo, hi);
    u32 out; __builtin_memcpy(&out, &r, sizeof(out));
    return out;
#else
    return ((u32)f2bf(hi) << 16) | (u32)f2bf(lo);
#endif
}

__device__ __forceinline__ u32 pack_h2(float lo, float hi) {
#ifdef HAVE_PKRTZ
    auto r = __builtin_amdgcn_cvt_pkrtz(lo, hi);
    u32 out; __builtin_memcpy(&out, &r, sizeof(out));
    return out;
#else
    return ((u32)f2h(hi) << 16) | (u32)f2h(lo);
#endif
}

__device__ __forceinline__ u32 pk_add_h2(u32 a, u32 b) {
    u32 d; asm("v_pk_add_f16 %0, %1, %2" : "=v"(d) : "v"(a), "v"(b)); return d;
}
__device__ __forceinline__ u32 pk_relu_h2(u32 a) {
    u32 d, z = 0u;
    asm("v_pk_max_f16 %0, %1, %2" : "=v"(d) : "v"(a), "v"(z)); return d;
}
__device__ __forceinline__ half8 as_h8(short8 s) {
    half8 h; __builtin_memcpy(&h, &s, 16); return h;
}

// ---------------------------------------------------------------------------
// Weight prep (blocks 0..320) fused with CSR histogram (blocks 321..).
// frag regions (u16): w1e @0 ([16][4][64][8] bf16), w1n @32768 ([16][2][64][8]),
//                     w2e' @49152 ([4][8][64][8] f16), w2n' @65536 (bf16).
// ---------------------------------------------------------------------------
__global__ __launch_bounds__(256) void weight_prep_hist(
    const float* __restrict__ ew1, const float* __restrict__ nw1,
    const float* __restrict__ ew2, const float* __restrict__ nw2,
    const float* __restrict__ dw,  const float* __restrict__ db,
    const float* __restrict__ eb2, const float* __restrict__ nb2,
    const int* __restrict__ edges, int* __restrict__ curU, int* __restrict__ curV,
    u16* __restrict__ frag, float* __restrict__ bias2)
{
    int blk = blockIdx.x, t = threadIdx.x;
    if (blk >= 321) {                       // CSR histogram (independent work)
        int e = (blk - 321) * 256 + t;
        if (e < NE) {
            atomicAdd(&curU[edges[2*e]], 1);
            atomicAdd(&curV[edges[2*e+1]], 1);
        }
        return;
    }
    if (blk < 192) {
        int idx = blk * 256 + t;                 // 0..49151
        const float* src; int KB, local;
        if (idx < 32768) { local = idx;         src = ew1; KB = 4; }
        else             { local = idx - 32768; src = nw1; KB = 2; }
        int j = local & 7, l = (local >> 3) & 63, rest = local >> 9;
        int kblk = rest % KB, ntile = rest / KB;
        int n = ntile * 16 + (l & 15);
        int k = kblk * 32 + ((l >> 4) << 3) + j;
        frag[idx] = f2bf(src[k * 256 + n]);
    } else if (blk < 320) {
        int idx = (blk - 192) * 256 + t;         // 0..32767
        bool is_e = (idx < 16384);
        const float* src = is_e ? ew2 : nw2;
        int local = idx & 16383;
        int j = local & 7, l = (local >> 3) & 63, rest = local >> 9;
        int kblk = rest & 7, ntile = rest >> 3;
        int n = ntile * 16 + (l & 15);
        int k = kblk * 32 + ((l >> 4) << 3) + j;
        float s = 0.f;
        for (int jj = 0; jj < 128; ++jj) s = fmaf(src[k * 128 + jj], dw[jj * 64 + n], s);
        frag[49152 + idx] = is_e ? f2h(s) : f2bf(s);
    } else if (t < 128) {
        int d = t & 63;
        const float* bsrc = (t >= 64) ? nb2 : eb2;
        float s = 0.f;
        #pragma unroll 4
        for (int j = 0; j < 128; ++j) s = fmaf(bsrc[j], dw[j * 64 + d], s);
        if (t >= 64) bias2[64 + d] = s + db[d];
        else         bias2[d] = s;
    }
}

// ---------------------------------------------------------------------------
// scan passes 2/3 (y = 0 -> U, y = 1 -> V)
// ---------------------------------------------------------------------------
__global__ __launch_bounds__(256) void scan_pass2d(const int* __restrict__ bsum2,
                                                   int* __restrict__ boff2) {
    __shared__ int s[256];
    const int t = threadIdx.x;
    const int base = blockIdx.y * (NSB + 1);
    s[t] = (t < NSB) ? bsum2[base + t] : 0;
    __syncthreads();
    for (int d = 1; d < 256; d <<= 1) {
        int v = (t >= d) ? s[t - d] : 0;
        __syncthreads();
        s[t] += v;
        __syncthreads();
    }
    if (t <= NSB) boff2[base + t] = (t == 0) ? 0 : s[t - 1];
}

__global__ __launch_bounds__(256) void scan_pass3d(int* __restrict__ curU,
                                                   int* __restrict__ curV,
                                                   const int* __restrict__ boff2,
                                                   int* __restrict__ uoff,
                                                   int* __restrict__ voff) {
    __shared__ int s[256];
    const int t = threadIdx.x;
    int* cursor = blockIdx.y ? curV : curU;
    int* off    = blockIdx.y ? voff : uoff;
    const int base = blockIdx.y * (NSB + 1);
    int i = blockIdx.x * 256 + t;
    int v = (i < NN) ? cursor[i] : 0;
    s[t] = v;
    __syncthreads();
    for (int d = 1; d < 256; d <<= 1) {
        int p = (t >= d) ? s[t - d] : 0;
        __syncthreads();
        s[t] += p;
        __syncthreads();
    }
    int excl = boff2[base + blockIdx.x] + s[t] - v;
    if (i < NN) { off[i] = excl; cursor[i] = excl; }
    if (i == NN - 1) off[NN] = excl + v;
}

// ---------------------------------------------------------------------------
// Fused CSR fill: u-slot (uv row + slot id) and v-slot (vmap -> u-slot).
// ---------------------------------------------------------------------------
__global__ __launch_bounds__(256) void csr_fill2(const int* __restrict__ edges,
                                                 int* __restrict__ curU,
                                                 int* __restrict__ curV,
                                                 int2* __restrict__ uv,
                                                 int* __restrict__ vmap) {
    int e = blockIdx.x * 256 + threadIdx.x;
    if (e < NE) {
        int u = edges[2*e], v = edges[2*e+1];
        int s0 = atomicAdd(&curU[u], 1);
        uv[s0] = make_int2(u, v);
        int s1 = atomicAdd(&curV[v], 1);
        vmap[s1] = s0;
    }
}

// ---------------------------------------------------------------------------
// Node MLP (dw-fused) + edge-MLP per-node halves At/Ab for ALL BN rows.
// 24 KB LDS; hidden dim processed in two 128-wide halves. Also absorbs
// scan_pass1 (blocks >= NODE_NB).
// ---------------------------------------------------------------------------
__global__ __launch_bounds__(256) void node_mlp_kernel(
    const float* __restrict__ x, const float* __restrict__ nb1,
    const float* __restrict__ eb1, const float* __restrict__ bias2,
    const u16* __restrict__ frag,
    u16* __restrict__ At, u16* __restrict__ Ab, float* __restrict__ out,
    const int* __restrict__ curU, const int* __restrict__ curV,
    int* __restrict__ bsum2)
{
    __shared__ u16 xs[64 * 64];     // 8 KB, 8 chunks/row, swizzle mask 7
    __shared__ u16 hid[64 * 128];   // 16 KB, 16 chunks/row, swizzle mask 15
    const int t = threadIdx.x;

    if (blockIdx.x >= NODE_NB) {    // fused scan_pass1 for U and V histograms
        int sb = blockIdx.x - NODE_NB;       // 0..2*NSB-1
        int y = sb / NSB, xi = sb - y * NSB;
        const int* cursor = y ? curV : curU;
        int* s = (int*)xs;
        int i = xi * 256 + t;
        s[t] = (i < NN) ? cursor[i] : 0;
        __syncthreads();
        for (int d = 128; d > 0; d >>= 1) {
            if (t < d) s[t] += s[t + d];
            __syncthreads();
        }
        if (t == 0) bsum2[y * (NSB + 1) + xi] = s[0];
        return;
    }

    const int wave = t >> 6, l = t & 63, lane15 = l & 15, quad = l >> 4;
    const int r0 = blockIdx.x * 64;
    const int valid = min(64, BN - r0);

    // stage + convert x -> xs (bf16)
    #pragma unroll
    for (int it = 0; it < 4; ++it) {
        int i = t + it * 256;          // 0..1023
        int m = i >> 4, c4 = i & 15;   // row, float4-col (8B half-chunk)
        int row = min(r0 + m, BN - 1);
        float4 g = ((const float4*)x)[(size_t)row * 16 + c4];
        uint2 q = make_uint2(pack_bf(g.x, g.y), pack_bf(g.z, g.w));
        int chunk = c4 >> 1;
        *(uint2*)(xs + m * 64 + ((chunk ^ (m & 7)) << 3) + (c4 & 1) * 4) = q;
    }
    __syncthreads();

    // Node MLP: GEMM1 in two hidden halves, GEMM2 accumulates across halves.
    f32x4 acc2[4];
    #pragma unroll
    for (int mt = 0; mt < 4; ++mt) acc2[mt] = f32x4{0.f,0.f,0.f,0.f};
    const u16* w1n = frag + 32768;   // [16 ntile][2 kblk][64][8]
    const u16* w2n = frag + 65536;   // [4 ntile][8 kblk][64][8]
    #pragma unroll
    for (int H = 0; H < 2; ++H) {
        f32x4 acc1[2][4];
        #pragma unroll
        for (int i = 0; i < 2; ++i)
            #pragma unroll
            for (int mt = 0; mt < 4; ++mt) acc1[i][mt] = f32x4{0.f,0.f,0.f,0.f};
        #pragma unroll
        for (int kblk = 0; kblk < 2; ++kblk) {
            short8 bf[4], af[2];
            int chunk = kblk * 4 + quad;
            #pragma unroll
            for (int mt = 0; mt < 4; ++mt) {
                int row = mt*16 + lane15;
                bf[mt] = *(const short8*)(xs + row * 64 + ((chunk ^ (row & 7)) << 3));
            }
            #pragma unroll
            for (int i = 0; i < 2; ++i)
                af[i] = *(const short8*)(w1n + (((H*8 + wave*2 + i)*2 + kblk)*64 + l) * 8);
            #pragma unroll
            for (int i = 0; i < 2; ++i)
                #pragma unroll
                for (int mt = 0; mt < 4; ++mt)
                    acc1[i][mt] = __builtin_amdgcn_mfma_f32_16x16x32_bf16(af[i], bf[mt], acc1[i][mt], 0, 0, 0);
        }
        // epilogue: relu+bias -> bf16 hid half (cols [H*128, H*128+128))
        #pragma unroll
        for (int i = 0; i < 2; ++i) {
            int ntl = wave*2 + i;                  // local col-tile 0..7
            int n0 = (H*8 + ntl)*16 + quad*4;      // global hidden col
            int c16 = ntl*2 + (quad >> 1);         // local 16B chunk 0..15
            float4 bv = *(const float4*)(nb1 + n0);
            #pragma unroll
            for (int mt = 0; mt < 4; ++mt) {
                int row = mt*16 + lane15;
                uint2 q = make_uint2(
                    pack_bf(fmaxf(acc1[i][mt][0] + bv.x, 0.f), fmaxf(acc1[i][mt][1] + bv.y, 0.f)),
                    pack_bf(fmaxf(acc1[i][mt][2] + bv.z, 0.f), fmaxf(acc1[i][mt][3] + bv.w, 0.f)));
                *(uint2*)(hid + row * 128 + ((c16 ^ (row & 15)) << 3) + (quad & 1) * 4) = q;
            }
        }
        __syncthreads();
        // GEMM2 partial over this K-half
        #pragma unroll
        for (int kb = 0; kb < 4; ++kb) {
            short8 bf[4], af;
            int chunk = kb * 4 + quad;
            #pragma unroll
            for (int mt = 0; mt < 4; ++mt) {
                int row = mt*16 + lane15;
                bf[mt] = *(const short8*)(hid + row * 128 + ((chunk ^ (row & 15)) << 3));
            }
            af = *(const short8*)(w2n + ((wave*8 + H*4 + kb)*64 + l) * 8);
            #pragma unroll
            for (int mt = 0; mt < 4; ++mt)
                acc2[mt] = __builtin_amdgcn_mfma_f32_16x16x32_bf16(af, bf[mt], acc2[mt], 0, 0, 0);
        }
        __syncthreads();   // hid reusable (next half / edge phase)
    }
    {   // node output store (f32)
        int n0 = wave*16 + quad*4;
        float4 bv = *(const float4*)(bias2 + 64 + n0);
        #pragma unroll
        for (int mt = 0; mt < 4; ++mt) {
            int m = mt*16 + lane15;
            if (m < valid) {
                float4 o;
                o.x = acc2[mt][0] + bv.x; o.y = acc2[mt][1] + bv.y;
                o.z = acc2[mt][2] + bv.z; o.w = acc2[mt][3] + bv.w;
                *(float4*)(out + (size_t)(r0 + m) * 64 + n0) = o;
            }
        }
    }

    // Edge per-node halves: T=0 -> At (+eb1), T=1 -> Ab; each in 2 hidden halves.
    const u16* w1e = frag;   // [16 ntile][4 kblk][64][8]; kblk 0-1 = top, 2-3 = bot
    #pragma unroll
    for (int T = 0; T < 2; ++T) {
        u16* dst = T ? Ab : At;
        #pragma unroll
        for (int H = 0; H < 2; ++H) {
            f32x4 acc[2][4];
            #pragma unroll
            for (int i = 0; i < 2; ++i)
                #pragma unroll
                for (int mt = 0; mt < 4; ++mt) acc[i][mt] = f32x4{0.f,0.f,0.f,0.f};
            #pragma unroll
            for (int kblk = 0; kblk < 2; ++kblk) {
                short8 bf[4], af[2];
                int chunk = kblk * 4 + quad;
                #pragma unroll
                for (int mt = 0; mt < 4; ++mt) {
                    int row = mt*16 + lane15;
                    bf[mt] = *(const short8*)(xs + row * 64 + ((chunk ^ (row & 7)) << 3));
                }
                #pragma unroll
                for (int i = 0; i < 2; ++i)
                    af[i] = *(const short8*)(w1e + (((H*8 + wave*2 + i)*4 + T*2 + kblk)*64 + l) * 8);
                #pragma unroll
                for (int i = 0; i < 2; ++i)
                    #pragma unroll
                    for (int mt = 0; mt < 4; ++mt)
                        acc[i][mt] = __builtin_amdgcn_mfma_f32_16x16x32_bf16(af[i], bf[mt], acc[i][mt], 0, 0, 0);
            }
            // epilogue -> f16 hid half
            #pragma unroll
            for (int i = 0; i < 2; ++i) {
                int ntl = wave*2 + i;
                int n0 = (H*8 + ntl)*16 + quad*4;
                int c16 = ntl*2 + (quad >> 1);
                float4 bv;
                if (T == 0) bv = *(const float4*)(eb1 + n0);
                else        bv = make_float4(0.f, 0.f, 0.f, 0.f);
                #pragma unroll
                for (int mt = 0; mt < 4; ++mt) {
                    int row = mt*16 + lane15;
                    uint2 q = make_uint2(
                        pack_h2(acc[i][mt][0] + bv.x, acc[i][mt][1] + bv.y),
                        pack_h2(acc[i][mt][2] + bv.z, acc[i][mt][3] + bv.w));
                    *(uint2*)(hid + row * 128 + ((c16 ^ (row & 15)) << 3) + (quad & 1) * 4) = q;
                }
            }
            __syncthreads();
            // store half-rows (256B contiguous per row)
            #pragma unroll
            for (int it = 0; it < 4; ++it) {
                int i = t + it * 256;          // 0..1023
                int m = i >> 4, c = i & 15;
                if (m < valid)
                    ((uint4*)dst)[((size_t)(r0 + m)) * 32 + H*16 + c] =
                        *(const uint4*)(hid + m * 128 + ((c ^ (m & 15)) << 3));
            }
            __syncthreads();   // hid reuse next (T,H)
        }
    }
}

// ---------------------------------------------------------------------------
// Edge combine + GEMM2 over u-SORTED edges, BOTH batches per block (4-phase,
// reg-prefetch, coalesced row loads). perm rows stored NON-TEMPORAL (write-
// once, read-once) so At/Ab stay resident in the memory-side cache.
// One 256B interleaved perm row per edge ([batch0 128B][batch1 128B]).
// ---------------------------------------------------------------------------
__global__ __launch_bounds__(256) void edge_emb3_kernel(
    const u16* __restrict__ At, const u16* __restrict__ Ab,
    const int2* __restrict__ uv, const float* __restrict__ bias2,
    const u16* __restrict__ frag, u16* __restrict__ perm)
{
    __shared__ u16 hid[64 * 128];   // 16 KB f16, 16 chunks/row, mask 15
    __shared__ int us[64], vs[64];
    const int t = threadIdx.x;
    const int wave = t >> 6, l = t & 63, lane15 = l & 15, quad = l >> 4;
    const int e0 = blockIdx.x * 64;
    const int valid = min(64, NE - e0);

    if (t < 64) {
        int2 p = uv[min(e0 + t, NE - 1)];
        us[t] = p.x;
        vs[t] = p.y;
    }
    __syncthreads();

    // per-thread gather geometry: 4 (m,c) pairs; c fixed = t&15
    const int c = t & 15;
    const uint4* atb[2] = { (const uint4*)At, (const uint4*)(At + (size_t)NN * 256) };
    const uint4* abb[2] = { (const uint4*)Ab, (const uint4*)(Ab + (size_t)NN * 256) };
    int  mrow[4]; u32 ubase[4], vbase[4];
    #pragma unroll
    for (int it = 0; it < 4; ++it) {
        int m = (t + it * 256) >> 4;
        mrow[it]  = m;
        ubase[it] = (u32)us[m] * 32;
        vbase[it] = (u32)vs[m] * 32;
    }

    // prologue: phase 0 (b=0, half=0) gather into registers
    uint4 pa[4], pb[4];
    #pragma unroll
    for (int it = 0; it < 4; ++it) {
        pa[it] = atb[0][(size_t)ubase[it] + c];
        pb[it] = abb[0][(size_t)vbase[it] + c];
    }

    const u16* w2 = frag + 49152;    // [4 ntile][8 kblk][64][8] f16, ntile = wave
    f32x4 accB[2][4];
    #pragma unroll
    for (int b = 0; b < 2; ++b)
        #pragma unroll
        for (int mt = 0; mt < 4; ++mt) accB[b][mt] = f32x4{0.f,0.f,0.f,0.f};

    #pragma unroll
    for (int p = 0; p < 4; ++p) {
        const int b = p >> 1, half = p & 1;
        // combine from regs -> LDS
        #pragma unroll
        for (int it = 0; it < 4; ++it) {
            uint4 r;
            r.x = pk_relu_h2(pk_add_h2(pa[it].x, pb[it].x));
            r.y = pk_relu_h2(pk_add_h2(pa[it].y, pb[it].y));
            r.z = pk_relu_h2(pk_add_h2(pa[it].z, pb[it].z));
            r.w = pk_relu_h2(pk_add_h2(pa[it].w, pb[it].w));
            int m = mrow[it];
            *(uint4*)(hid + m * 128 + ((c ^ (m & 15)) << 3)) = r;
        }
        // issue next phase's gather (stays in flight under the MFMA below)
        if (p < 3) {
            const int nb = (p + 1) >> 1, nh = (p + 1) & 1;
            #pragma unroll
            for (int it = 0; it < 4; ++it) {
                pa[it] = atb[nb][(size_t)ubase[it] + nh * 16 + c];
                pb[it] = abb[nb][(size_t)vbase[it] + nh * 16 + c];
            }
        }
        __syncthreads();
        // GEMM2^T quarter: N=64, K=128 (this half), f16 MFMA
        #pragma unroll
        for (int kb = 0; kb < 4; ++kb) {
            short8 bf[4], af;
            int chunk = kb * 4 + quad;
            #pragma unroll
            for (int mt = 0; mt < 4; ++mt) {
                int row = mt*16 + lane15;
                bf[mt] = *(const short8*)(hid + row * 128 + ((chunk ^ (row & 15)) << 3));
            }
            af = *(const short8*)(w2 + ((wave*8 + half*4 + kb)*64 + l) * 8);
            #pragma unroll
            for (int mt = 0; mt < 4; ++mt)
                accB[b][mt] = __builtin_amdgcn_mfma_f32_16x16x32_f16(as_h8(af), as_h8(bf[mt]), accB[b][mt], 0, 0, 0);
        }
        __syncthreads();   // hid reusable
    }

    {   // epilogue: both batches' bf16 rows into hid (256B/edge, mask 15)
        int n0 = wave*16 + quad*4;
        float4 bv = *(const float4*)(bias2 + n0);
        #pragma unroll
        for (int b = 0; b < 2; ++b) {
            int cc = b*8 + wave*2 + (quad >> 1);   // 16B chunk 0..15
            #pragma unroll
            for (int mt = 0; mt < 4; ++mt) {
                int m = mt*16 + lane15;
                uint2 q = make_uint2(
                    pack_bf(accB[b][mt][0] + bv.x, accB[b][mt][1] + bv.y),
                    pack_bf(accB[b][mt][2] + bv.z, accB[b][mt][3] + bv.w));
                *(uint2*)(hid + m * 128 + ((cc ^ (m & 15)) << 3) + (quad & 1) * 4) = q;
            }
        }
    }
    __syncthreads();

    // store: one 256B interleaved row per edge, NON-TEMPORAL (don't evict
    // the At/Ab working set from the memory-side cache)
    #pragma unroll
    for (int it = 0; it < 4; ++it) {
        int i = t + it * 256;          // 0..1023
        int m = i >> 4, cc = i & 15;
        if (m < valid) {
            nt4 val = *(const nt4*)(hid + m * 128 + ((cc ^ (m & 15)) << 3));
            __builtin_nontemporal_store(val, (nt4*)perm + ((size_t)(e0 + m)) * 16 + cc);
        }
    }
}

// ---------------------------------------------------------------------------
// FUSED gather: perm rows are 256B = [batch0 128B][batch1 128B]. One pass
// accumulates both batches for node n (u-run contiguous + v-list indirect).
// perm reads are non-temporal (read-once stream).
// ---------------------------------------------------------------------------
#define ACCUM8(q) { union { u32 u; float f; } xx;                         \
    xx.u = (q).x << 16;          a0 += xx.f;                              \
    xx.u = (q).x & 0xffff0000u;  a1 += xx.f;                              \
    xx.u = (q).y << 16;          a2 += xx.f;                              \
    xx.u = (q).y & 0xffff0000u;  a3 += xx.f;                              \
    xx.u = (q).z << 16;          a4 += xx.f;                              \
    xx.u = (q).z & 0xffff0000u;  a5 += xx.f;                              \
    xx.u = (q).w << 16;          a6 += xx.f;                              \
    xx.u = (q).w & 0xffff0000u;  a7 += xx.f; }

__global__ __launch_bounds__(256) void gather4_kernel(
    const u32* __restrict__ perm32, const int* __restrict__ uoff,
    const int* __restrict__ voff, const int* __restrict__ vmap,
    float* __restrict__ out)
{
    const int t = threadIdx.x, wave = t >> 6, l = t & 63;
    const int n = blockIdx.x * 4 + wave;
    const int ub = uoff[n], ucnt = uoff[n + 1] - ub;
    const int vb = voff[n], vcnt = voff[n + 1] - vb;
    if ((ucnt | vcnt) == 0) return;
    const int sg = l >> 4, c16 = l & 15;   // 4 slots/group, 16B col in 256B row
    float a0=0.f,a1=0.f,a2=0.f,a3=0.f,a4=0.f,a5=0.f,a6=0.f,a7=0.f;

    for (int j0 = 0; j0 < ucnt; j0 += 8) {
        int jA = j0 + sg, jB = j0 + 4 + sg;
        nt4 qA = __builtin_nontemporal_load(
            (const nt4*)(perm32 + (size_t)(ub + min(jA, ucnt - 1)) * 64 + c16 * 4));
        nt4 qB = __builtin_nontemporal_load(
            (const nt4*)(perm32 + (size_t)(ub + min(jB, ucnt - 1)) * 64 + c16 * 4));
        if (jA < ucnt) ACCUM8(qA);
        if (jB < ucnt) ACCUM8(qB);
    }
    for (int j0 = 0; j0 < vcnt; j0 += 8) {
        int jA = j0 + sg, jB = j0 + 4 + sg;
        int pA = vmap[vb + min(jA, vcnt - 1)];
        int pB = vmap[vb + min(jB, vcnt - 1)];
        nt4 qA = __builtin_nontemporal_load(
            (const nt4*)(perm32 + (size_t)pA * 64 + c16 * 4));
        nt4 qB = __builtin_nontemporal_load(
            (const nt4*)(perm32 + (size_t)pB * 64 + c16 * 4));
        if (jA < vcnt) ACCUM8(qA);
        if (jB < vcnt) ACCUM8(qB);
    }

    a0 += __shfl_xor(a0, 16); a1 += __shfl_xor(a1, 16);
    a2 += __shfl_xor(a2, 16); a3 += __shfl_xor(a3, 16);
    a4 += __shfl_xor(a4, 16); a5 += __shfl_xor(a5, 16);
    a6 += __shfl_xor(a6, 16); a7 += __shfl_xor(a7, 16);
    a0 += __shfl_xor(a0, 32); a1 += __shfl_xor(a1, 32);
    a2 += __shfl_xor(a2, 32); a3 += __shfl_xor(a3, 32);
    a4 += __shfl_xor(a4, 32); a5 += __shfl_xor(a5, 32);
    a6 += __shfl_xor(a6, 32); a7 += __shfl_xor(a7, 32);

    if (l < 16) {   // lane = c16: 0..7 -> batch0 cols, 8..15 -> batch1 cols
        float* p = out + ((size_t)((l >> 3) * NN + n)) * 64 + (l & 7) * 8;
        float4 h0 = *(float4*)p, h1 = *(float4*)(p + 4);
        h0.x += a0; h0.y += a1; h0.z += a2; h0.w += a3;
        h1.x += a4; h1.y += a5; h1.z += a6; h1.w += a7;
        *(float4*)p = h0; *(float4*)(p + 4) = h1;
    }
}

// ---------------------------------------------------------------------------
extern "C" void kernel_launch(void* const* d_in, const int* in_sizes, int n_in,
                              void* d_out, int out_size, void* d_ws, size_t ws_size,
                              hipStream_t stream) {
    const float* x     = (const float*)d_in[0];
    const int*   edges = (const int*)d_in[1];
    const float* ew1   = (const float*)d_in[2];
    const float* eb1   = (const float*)d_in[3];
    const float* ew2   = (const float*)d_in[4];
    const float* eb2   = (const float*)d_in[5];
    const float* nw1   = (const float*)d_in[6];
    const float* nb1   = (const float*)d_in[7];
    const float* nw2   = (const float*)d_in[8];
    const float* nb2   = (const float*)d_in[9];
    const float* dw    = (const float*)d_in[10];
    const float* db    = (const float*)d_in[11];
    float* out = (float*)d_out;    // [BN][64]

    // Workspace layout (512B aligned)
    char* w = (char*)d_ws;
    size_t o = 0;
    auto take = [&](size_t bytes) { char* p = w + o; o = (o + bytes + 511) & ~(size_t)511; return p; };
    u16*   frag   = (u16*)  take(81920 * 2);                   // 160 KB
    float* bias2  = (float*)take(128 * 4);
    int*   curU   = (int*)  take((size_t)NN * 4);
    int*   curV   = (int*)  take((size_t)NN * 4);
    int*   uoff   = (int*)  take((size_t)(NN + 1) * 4);
    int*   voff   = (int*)  take((size_t)(NN + 1) * 4);
    int*   bsum2  = (int*)  take((size_t)2 * (NSB + 1) * 4);
    int*   boff2  = (int*)  take((size_t)2 * (NSB + 1) * 4);
    int*   vmap   = (int*)  take((size_t)NE * 4);              // 2 MB
    int2*  uv     = (int2*) take((size_t)NE * 8);              // 4 MB
    u16*   At     = (u16*)  take((size_t)BN * 256 * 2);        // 51.2 MB (both batches)
    u16*   Ab     = (u16*)  take((size_t)BN * 256 * 2);        // 51.2 MB
    u16*   perm   = (u16*)  take((size_t)NE * 128 * 2);        // 128 MB (interleaved)
    (void)ws_size;

    // zero histograms (DMA memsets, replaces a dispatch)
    (void)hipMemsetAsync(curU, 0, (size_t)NN * 4, stream);
    (void)hipMemsetAsync(curV, 0, (size_t)NN * 4, stream);

    // weight prep || CSR histogram (independent work, one dispatch)
    weight_prep_hist<<<321 + (NE + 255) / 256, 256, 0, stream>>>(
        ew1, nw1, ew2, nw2, dw, db, eb2, nb2, edges, curU, curV, frag, bias2);

    // node+edge per-node tables || scan_pass1 (both axes)
    node_mlp_kernel<<<NODE_NB + 2 * NSB, 256, 0, stream>>>(
        x, nb1, eb1, bias2, frag, At, Ab, out, curU, curV, bsum2);

    scan_pass2d<<<dim3(1, 2), 256, 0, stream>>>(bsum2, boff2);
    scan_pass3d<<<dim3(NSB, 2), 256, 0, stream>>>(curU, curV, boff2, uoff, voff);
    csr_fill2<<<(NE + 255) / 256, 256, 0, stream>>>(edges, curU, curV, uv, vmap);

    // edge MLP both batches -> interleaved perm rows (nt stores)
    edge_emb3_kernel<<<(NE + 63) / 64, 256, 0, stream>>>(At, Ab, uv, bias2, frag, perm);

    // one gather for both batches (nt perm reads)
    gather4_kernel<<<NN / 4, 256, 0, stream>>>((const u32*)perm, uoff, voff, vmap, out);
}

// Round 16
// 407.446 us; speedup vs baseline: 1.0956x; 1.0061x over previous
//
#include <hip/hip_runtime.h>
#include <hip/hip_bf16.h>

// Problem constants
#define BB   2
#define NN   50000
#define BN   100000     // B*N
#define NE   500000
#define NSB  196        // scan blocks = ceil(NN/256)
#define NODE_NB 1563    // ceil(BN/64)

using u16 = unsigned short;
using u32 = unsigned int;
typedef __attribute__((ext_vector_type(8))) short short8;      // 8 x bf16/f16 bits
typedef __attribute__((ext_vector_type(8))) _Float16 half8;    // 8 x f16 (4 VGPRs)
typedef __attribute__((ext_vector_type(4))) float f32x4;       // MFMA accumulator
typedef __attribute__((ext_vector_type(4))) unsigned int nt4;  // native 16B vector (nt ld/st)

__device__ __forceinline__ u16 f2bf(float f) {   // RNE f32 -> bf16 (finite inputs)
    union { float f; u32 u; } w; w.f = f;
    return (u16)((w.u + 0x7fffu + ((w.u >> 16) & 1u)) >> 16);
}
__device__ __forceinline__ u16 f2h(float f) {    // RNE f32 -> f16
    _Float16 h = (_Float16)f; u16 u; __builtin_memcpy(&u, &h, 2); return u;
}

#if defined(__has_builtin)
#if __has_builtin(__builtin_amdgcn_cvt_pk_bf16_f32)
#define HAVE_CVTPK 1
#endif
#if __has_builtin(__builtin_amdgcn_cvt_pkrtz)
#define HAVE_PKRTZ 1
#endif
#endif

__device__ __forceinline__ u32 pack_bf(float lo, float hi) {
#ifdef HAVE_CVTPK
    auto r = __builtin_amdgcn_cvt_pk_bf16_f32(lo, hi);
    u32 out; __builtin_memcpy(&out, &r, sizeof(out));
    return out;
#else
    return ((u32)f2bf(hi) << 16) | (u32)f2bf(lo);
#endif
}

__device__ __forceinline__ u32 pack_h2(float lo, float hi) {
#ifdef HAVE_PKRTZ
    auto r = __builtin_amdgcn_cvt_pkrtz(lo, hi);
    u32 out; __builtin_memcpy(&out, &r, sizeof(out));
    return out;
#else
    return ((u32)f2h(hi) << 16) | (u32)f2h(lo);
#endif
}

__device__ __forceinline__ u32 pk_add_h2(u32 a, u32 b) {
    u32 d; asm("v_pk_add_f16 %0, %1, %2" : "=v"(d) : "v"(a), "v"(b)); return d;
}
__device__ __forceinline__ u32 pk_relu_h2(u32 a) {
    u32 d, z = 0u;
    asm("v_pk_max_f16 %0, %1, %2" : "=v"(d) : "v"(a), "v"(z)); return d;
}
__device__ __forceinline__ half8 as_h8(short8 s) {
    half8 h; __builtin_memcpy(&h, &s, 16); return h;
}

// ---------------------------------------------------------------------------
// Weight prep (blocks 0..320) fused with CSR histogram (blocks 321..).
// frag regions (u16): w1e @0 ([16][4][64][8] bf16), w1n @32768 ([16][2][64][8]),
//                     w2e' @49152 ([4][8][64][8] f16), w2n' @65536 (bf16).
// ---------------------------------------------------------------------------
__global__ __launch_bounds__(256) void weight_prep_hist(
    const float* __restrict__ ew1, const float* __restrict__ nw1,
    const float* __restrict__ ew2, const float* __restrict__ nw2,
    const float* __restrict__ dw,  const float* __restrict__ db,
    const float* __restrict__ eb2, const float* __restrict__ nb2,
    const int* __restrict__ edges, int* __restrict__ curU, int* __restrict__ curV,
    u16* __restrict__ frag, float* __restrict__ bias2)
{
    int blk = blockIdx.x, t = threadIdx.x;
    if (blk >= 321) {                       // CSR histogram (independent work)
        int e = (blk - 321) * 256 + t;
        if (e < NE) {
            atomicAdd(&curU[edges[2*e]], 1);
            atomicAdd(&curV[edges[2*e+1]], 1);
        }
        return;
    }
    if (blk < 192) {
        int idx = blk * 256 + t;                 // 0..49151
        const float* src; int KB, local;
        if (idx < 32768) { local = idx;         src = ew1; KB = 4; }
        else             { local = idx - 32768; src = nw1; KB = 2; }
        int j = local & 7, l = (local >> 3) & 63, rest = local >> 9;
        int kblk = rest % KB, ntile = rest / KB;
        int n = ntile * 16 + (l & 15);
        int k = kblk * 32 + ((l >> 4) << 3) + j;
        frag[idx] = f2bf(src[k * 256 + n]);
    } else if (blk < 320) {
        int idx = (blk - 192) * 256 + t;         // 0..32767
        bool is_e = (idx < 16384);
        const float* src = is_e ? ew2 : nw2;
        int local = idx & 16383;
        int j = local & 7, l = (local >> 3) & 63, rest = local >> 9;
        int kblk = rest & 7, ntile = rest >> 3;
        int n = ntile * 16 + (l & 15);
        int k = kblk * 32 + ((l >> 4) << 3) + j;
        float s = 0.f;
        for (int jj = 0; jj < 128; ++jj) s = fmaf(src[k * 128 + jj], dw[jj * 64 + n], s);
        frag[49152 + idx] = is_e ? f2h(s) : f2bf(s);
    } else if (t < 128) {
        int d = t & 63;
        const float* bsrc = (t >= 64) ? nb2 : eb2;
        float s = 0.f;
        #pragma unroll 4
        for (int j = 0; j < 128; ++j) s = fmaf(bsrc[j], dw[j * 64 + d], s);
        if (t >= 64) bias2[64 + d] = s + db[d];
        else         bias2[d] = s;
    }
}

// ---------------------------------------------------------------------------
// scan passes 2/3 (y = 0 -> U, y = 1 -> V)
// ---------------------------------------------------------------------------
__global__ __launch_bounds__(256) void scan_pass2d(const int* __restrict__ bsum2,
                                                   int* __restrict__ boff2) {
    __shared__ int s[256];
    const int t = threadIdx.x;
    const int base = blockIdx.y * (NSB + 1);
    s[t] = (t < NSB) ? bsum2[base + t] : 0;
    __syncthreads();
    for (int d = 1; d < 256; d <<= 1) {
        int v = (t >= d) ? s[t - d] : 0;
        __syncthreads();
        s[t] += v;
        __syncthreads();
    }
    if (t <= NSB) boff2[base + t] = (t == 0) ? 0 : s[t - 1];
}

__global__ __launch_bounds__(256) void scan_pass3d(int* __restrict__ curU,
                                                   int* __restrict__ curV,
                                                   const int* __restrict__ boff2,
                                                   int* __restrict__ uoff,
                                                   int* __restrict__ voff) {
    __shared__ int s[256];
    const int t = threadIdx.x;
    int* cursor = blockIdx.y ? curV : curU;
    int* off    = blockIdx.y ? voff : uoff;
    const int base = blockIdx.y * (NSB + 1);
    int i = blockIdx.x * 256 + t;
    int v = (i < NN) ? cursor[i] : 0;
    s[t] = v;
    __syncthreads();
    for (int d = 1; d < 256; d <<= 1) {
        int p = (t >= d) ? s[t - d] : 0;
        __syncthreads();
        s[t] += p;
        __syncthreads();
    }
    int excl = boff2[base + blockIdx.x] + s[t] - v;
    if (i < NN) { off[i] = excl; cursor[i] = excl; }
    if (i == NN - 1) off[NN] = excl + v;
}

// ---------------------------------------------------------------------------
// Fused CSR fill: u-slot (uv row + slot id) and v-slot (vmap -> u-slot).
// ---------------------------------------------------------------------------
__global__ __launch_bounds__(256) void csr_fill2(const int* __restrict__ edges,
                                                 int* __restrict__ curU,
                                                 int* __restrict__ curV,
                                                 int2* __restrict__ uv,
                                                 int* __restrict__ vmap) {
    int e = blockIdx.x * 256 + threadIdx.x;
    if (e < NE) {
        int u = edges[2*e], v = edges[2*e+1];
        int s0 = atomicAdd(&curU[u], 1);
        uv[s0] = make_int2(u, v);
        int s1 = atomicAdd(&curV[v], 1);
        vmap[s1] = s0;
    }
}

// ---------------------------------------------------------------------------
// Node MLP (dw-fused) + edge-MLP per-node halves At/Ab for ALL BN rows.
// At/Ab layout is BATCH-INTERLEAVED: [node][batch][256] f16, so per edge the
// two batches' rows form one contiguous 512B region (halves the random-access
// count in edge_emb3). 24 KB LDS; hidden dim in two 128-wide halves. Also
// absorbs scan_pass1 (blocks >= NODE_NB).
// ---------------------------------------------------------------------------
__global__ __launch_bounds__(256) void node_mlp_kernel(
    const float* __restrict__ x, const float* __restrict__ nb1,
    const float* __restrict__ eb1, const float* __restrict__ bias2,
    const u16* __restrict__ frag,
    u16* __restrict__ At, u16* __restrict__ Ab, float* __restrict__ out,
    const int* __restrict__ curU, const int* __restrict__ curV,
    int* __restrict__ bsum2)
{
    __shared__ u16 xs[64 * 64];     // 8 KB, 8 chunks/row, swizzle mask 7
    __shared__ u16 hid[64 * 128];   // 16 KB, 16 chunks/row, swizzle mask 15
    const int t = threadIdx.x;

    if (blockIdx.x >= NODE_NB) {    // fused scan_pass1 for U and V histograms
        int sb = blockIdx.x - NODE_NB;       // 0..2*NSB-1
        int y = sb / NSB, xi = sb - y * NSB;
        const int* cursor = y ? curV : curU;
        int* s = (int*)xs;
        int i = xi * 256 + t;
        s[t] = (i < NN) ? cursor[i] : 0;
        __syncthreads();
        for (int d = 128; d > 0; d >>= 1) {
            if (t < d) s[t] += s[t + d];
            __syncthreads();
        }
        if (t == 0) bsum2[y * (NSB + 1) + xi] = s[0];
        return;
    }

    const int wave = t >> 6, l = t & 63, lane15 = l & 15, quad = l >> 4;
    const int r0 = blockIdx.x * 64;
    const int valid = min(64, BN - r0);

    // stage + convert x -> xs (bf16)
    #pragma unroll
    for (int it = 0; it < 4; ++it) {
        int i = t + it * 256;          // 0..1023
        int m = i >> 4, c4 = i & 15;   // row, float4-col (8B half-chunk)
        int row = min(r0 + m, BN - 1);
        float4 g = ((const float4*)x)[(size_t)row * 16 + c4];
        uint2 q = make_uint2(pack_bf(g.x, g.y), pack_bf(g.z, g.w));
        int chunk = c4 >> 1;
        *(uint2*)(xs + m * 64 + ((chunk ^ (m & 7)) << 3) + (c4 & 1) * 4) = q;
    }
    __syncthreads();

    // Node MLP: GEMM1 in two hidden halves, GEMM2 accumulates across halves.
    f32x4 acc2[4];
    #pragma unroll
    for (int mt = 0; mt < 4; ++mt) acc2[mt] = f32x4{0.f,0.f,0.f,0.f};
    const u16* w1n = frag + 32768;   // [16 ntile][2 kblk][64][8]
    const u16* w2n = frag + 65536;   // [4 ntile][8 kblk][64][8]
    #pragma unroll
    for (int H = 0; H < 2; ++H) {
        f32x4 acc1[2][4];
        #pragma unroll
        for (int i = 0; i < 2; ++i)
            #pragma unroll
            for (int mt = 0; mt < 4; ++mt) acc1[i][mt] = f32x4{0.f,0.f,0.f,0.f};
        #pragma unroll
        for (int kblk = 0; kblk < 2; ++kblk) {
            short8 bf[4], af[2];
            int chunk = kblk * 4 + quad;
            #pragma unroll
            for (int mt = 0; mt < 4; ++mt) {
                int row = mt*16 + lane15;
                bf[mt] = *(const short8*)(xs + row * 64 + ((chunk ^ (row & 7)) << 3));
            }
            #pragma unroll
            for (int i = 0; i < 2; ++i)
                af[i] = *(const short8*)(w1n + (((H*8 + wave*2 + i)*2 + kblk)*64 + l) * 8);
            #pragma unroll
            for (int i = 0; i < 2; ++i)
                #pragma unroll
                for (int mt = 0; mt < 4; ++mt)
                    acc1[i][mt] = __builtin_amdgcn_mfma_f32_16x16x32_bf16(af[i], bf[mt], acc1[i][mt], 0, 0, 0);
        }
        // epilogue: relu+bias -> bf16 hid half (cols [H*128, H*128+128))
        #pragma unroll
        for (int i = 0; i < 2; ++i) {
            int ntl = wave*2 + i;                  // local col-tile 0..7
            int n0 = (H*8 + ntl)*16 + quad*4;      // global hidden col
            int c16 = ntl*2 + (quad >> 1);         // local 16B chunk 0..15
            float4 bv = *(const float4*)(nb1 + n0);
            #pragma unroll
            for (int mt = 0; mt < 4; ++mt) {
                int row = mt*16 + lane15;
                uint2 q = make_uint2(
                    pack_bf(fmaxf(acc1[i][mt][0] + bv.x, 0.f), fmaxf(acc1[i][mt][1] + bv.y, 0.f)),
                    pack_bf(fmaxf(acc1[i][mt][2] + bv.z, 0.f), fmaxf(acc1[i][mt][3] + bv.w, 0.f)));
                *(uint2*)(hid + row * 128 + ((c16 ^ (row & 15)) << 3) + (quad & 1) * 4) = q;
            }
        }
        __syncthreads();
        // GEMM2 partial over this K-half
        #pragma unroll
        for (int kb = 0; kb < 4; ++kb) {
            short8 bf[4], af;
            int chunk = kb * 4 + quad;
            #pragma unroll
            for (int mt = 0; mt < 4; ++mt) {
                int row = mt*16 + lane15;
                bf[mt] = *(const short8*)(hid + row * 128 + ((chunk ^ (row & 15)) << 3));
            }
            af = *(const short8*)(w2n + ((wave*8 + H*4 + kb)*64 + l) * 8);
            #pragma unroll
            for (int mt = 0; mt < 4; ++mt)
                acc2[mt] = __builtin_amdgcn_mfma_f32_16x16x32_bf16(af, bf[mt], acc2[mt], 0, 0, 0);
        }
        __syncthreads();   // hid reusable (next half / edge phase)
    }
    {   // node output store (f32)
        int n0 = wave*16 + quad*4;
        float4 bv = *(const float4*)(bias2 + 64 + n0);
        #pragma unroll
        for (int mt = 0; mt < 4; ++mt) {
            int m = mt*16 + lane15;
            if (m < valid) {
                float4 o;
                o.x = acc2[mt][0] + bv.x; o.y = acc2[mt][1] + bv.y;
                o.z = acc2[mt][2] + bv.z; o.w = acc2[mt][3] + bv.w;
                *(float4*)(out + (size_t)(r0 + m) * 64 + n0) = o;
            }
        }
    }

    // Edge per-node halves: T=0 -> At (+eb1), T=1 -> Ab; each in 2 hidden halves.
    // Store to batch-interleaved layout: dst row = (node*2 + batch).
    const u16* w1e = frag;   // [16 ntile][4 kblk][64][8]; kblk 0-1 = top, 2-3 = bot
    #pragma unroll
    for (int T = 0; T < 2; ++T) {
        u16* dst = T ? Ab : At;
        #pragma unroll
        for (int H = 0; H < 2; ++H) {
            f32x4 acc[2][4];
            #pragma unroll
            for (int i = 0; i < 2; ++i)
                #pragma unroll
                for (int mt = 0; mt < 4; ++mt) acc[i][mt] = f32x4{0.f,0.f,0.f,0.f};
            #pragma unroll
            for (int kblk = 0; kblk < 2; ++kblk) {
                short8 bf[4], af[2];
                int chunk = kblk * 4 + quad;
                #pragma unroll
                for (int mt = 0; mt < 4; ++mt) {
                    int row = mt*16 + lane15;
                    bf[mt] = *(const short8*)(xs + row * 64 + ((chunk ^ (row & 7)) << 3));
                }
                #pragma unroll
                for (int i = 0; i < 2; ++i)
                    af[i] = *(const short8*)(w1e + (((H*8 + wave*2 + i)*4 + T*2 + kblk)*64 + l) * 8);
                #pragma unroll
                for (int i = 0; i < 2; ++i)
                    #pragma unroll
                    for (int mt = 0; mt < 4; ++mt)
                        acc[i][mt] = __builtin_amdgcn_mfma_f32_16x16x32_bf16(af[i], bf[mt], acc[i][mt], 0, 0, 0);
            }
            // epilogue -> f16 hid half
            #pragma unroll
            for (int i = 0; i < 2; ++i) {
                int ntl = wave*2 + i;
                int n0 = (H*8 + ntl)*16 + quad*4;
                int c16 = ntl*2 + (quad >> 1);
                float4 bv;
                if (T == 0) bv = *(const float4*)(eb1 + n0);
                else        bv = make_float4(0.f, 0.f, 0.f, 0.f);
                #pragma unroll
                for (int mt = 0; mt < 4; ++mt) {
                    int row = mt*16 + lane15;
                    uint2 q = make_uint2(
                        pack_h2(acc[i][mt][0] + bv.x, acc[i][mt][1] + bv.y),
                        pack_h2(acc[i][mt][2] + bv.z, acc[i][mt][3] + bv.w));
                    *(uint2*)(hid + row * 128 + ((c16 ^ (row & 15)) << 3) + (quad & 1) * 4) = q;
                }
            }
            __syncthreads();
            // store half-rows (256B contiguous per (row,H)) at interleaved slot
            #pragma unroll
            for (int it = 0; it < 4; ++it) {
                int i = t + it * 256;          // 0..1023
                int m = i >> 4, c = i & 15;
                if (m < valid) {
                    int row = r0 + m;                    // 0..BN-1
                    int bb  = row >= NN;                 // batch
                    int n   = bb ? row - NN : row;       // node
                    ((uint4*)dst)[((size_t)(n * 2 + bb)) * 32 + H*16 + c] =
                        *(const uint4*)(hid + m * 128 + ((c ^ (m & 15)) << 3));
                }
            }
            __syncthreads();   // hid reuse next (T,H)
        }
    }
}

// ---------------------------------------------------------------------------
// Edge combine + GEMM2 over u-SORTED edges, BOTH batches per block (4-phase,
// reg-prefetch). At/Ab are batch-interleaved [node][2][256] f16: per edge the
// random gather is ONE contiguous 512B region per table (half the access
// count of the split layout). perm rows stored NON-TEMPORAL.
// One 256B interleaved perm row per edge ([batch0 128B][batch1 128B]).
// ---------------------------------------------------------------------------
__global__ __launch_bounds__(256) void edge_emb3_kernel(
    const u16* __restrict__ At, const u16* __restrict__ Ab,
    const int2* __restrict__ uv, const float* __restrict__ bias2,
    const u16* __restrict__ frag, u16* __restrict__ perm)
{
    __shared__ u16 hid[64 * 128];   // 16 KB f16, 16 chunks/row, mask 15
    __shared__ int us[64], vs[64];
    const int t = threadIdx.x;
    const int wave = t >> 6, l = t & 63, lane15 = l & 15, quad = l >> 4;
    const int e0 = blockIdx.x * 64;
    const int valid = min(64, NE - e0);

    if (t < 64) {
        int2 p = uv[min(e0 + t, NE - 1)];
        us[t] = p.x;
        vs[t] = p.y;
    }
    __syncthreads();

    // per-thread gather geometry: 4 (m,c) pairs; c fixed = t&15
    const int c = t & 15;
    const uint4* at4 = (const uint4*)At;
    const uint4* ab4 = (const uint4*)Ab;
    int  mrow[4]; u32 ubase[4], vbase[4];
    #pragma unroll
    for (int it = 0; it < 4; ++it) {
        int m = (t + it * 256) >> 4;
        mrow[it]  = m;
        ubase[it] = (u32)us[m] * 64;   // node's 1KB region, uint4 units
        vbase[it] = (u32)vs[m] * 64;
    }

    // prologue: phase 0 (b=0, half=0) gather into registers
    uint4 pa[4], pb[4];
    #pragma unroll
    for (int it = 0; it < 4; ++it) {
        pa[it] = at4[(size_t)ubase[it] + c];
        pb[it] = ab4[(size_t)vbase[it] + c];
    }

    const u16* w2 = frag + 49152;    // [4 ntile][8 kblk][64][8] f16, ntile = wave
    f32x4 accB[2][4];
    #pragma unroll
    for (int b = 0; b < 2; ++b)
        #pragma unroll
        for (int mt = 0; mt < 4; ++mt) accB[b][mt] = f32x4{0.f,0.f,0.f,0.f};

    #pragma unroll
    for (int p = 0; p < 4; ++p) {
        const int b = p >> 1, half = p & 1;
        // combine from regs -> LDS
        #pragma unroll
        for (int it = 0; it < 4; ++it) {
            uint4 r;
            r.x = pk_relu_h2(pk_add_h2(pa[it].x, pb[it].x));
            r.y = pk_relu_h2(pk_add_h2(pa[it].y, pb[it].y));
            r.z = pk_relu_h2(pk_add_h2(pa[it].z, pb[it].z));
            r.w = pk_relu_h2(pk_add_h2(pa[it].w, pb[it].w));
            int m = mrow[it];
            *(uint4*)(hid + m * 128 + ((c ^ (m & 15)) << 3)) = r;
        }
        // issue next phase's gather (stays in flight under the MFMA below);
        // offset within node region: batch*32 + half*16 (uint4 units)
        if (p < 3) {
            const u32 noff = (u32)((((p + 1) >> 1) << 5) + (((p + 1) & 1) << 4));
            #pragma unroll
            for (int it = 0; it < 4; ++it) {
                pa[it] = at4[(size_t)ubase[it] + noff + c];
                pb[it] = ab4[(size_t)vbase[it] + noff + c];
            }
        }
        __syncthreads();
        // GEMM2^T quarter: N=64, K=128 (this half), f16 MFMA
        #pragma unroll
        for (int kb = 0; kb < 4; ++kb) {
            short8 bf[4], af;
            int chunk = kb * 4 + quad;
            #pragma unroll
            for (int mt = 0; mt < 4; ++mt) {
                int row = mt*16 + lane15;
                bf[mt] = *(const short8*)(hid + row * 128 + ((chunk ^ (row & 15)) << 3));
            }
            af = *(const short8*)(w2 + ((wave*8 + half*4 + kb)*64 + l) * 8);
            #pragma unroll
            for (int mt = 0; mt < 4; ++mt)
                accB[b][mt] = __builtin_amdgcn_mfma_f32_16x16x32_f16(as_h8(af), as_h8(bf[mt]), accB[b][mt], 0, 0, 0);
        }
        __syncthreads();   // hid reusable
    }

    {   // epilogue: both batches' bf16 rows into hid (256B/edge, mask 15)
        int n0 = wave*16 + quad*4;
        float4 bv = *(const float4*)(bias2 + n0);
        #pragma unroll
        for (int b = 0; b < 2; ++b) {
            int cc = b*8 + wave*2 + (quad >> 1);   // 16B chunk 0..15
            #pragma unroll
            for (int mt = 0; mt < 4; ++mt) {
                int m = mt*16 + lane15;
                uint2 q = make_uint2(
                    pack_bf(accB[b][mt][0] + bv.x, accB[b][mt][1] + bv.y),
                    pack_bf(accB[b][mt][2] + bv.z, accB[b][mt][3] + bv.w));
                *(uint2*)(hid + m * 128 + ((cc ^ (m & 15)) << 3) + (quad & 1) * 4) = q;
            }
        }
    }
    __syncthreads();

    // store: one 256B interleaved row per edge, NON-TEMPORAL
    #pragma unroll
    for (int it = 0; it < 4; ++it) {
        int i = t + it * 256;          // 0..1023
        int m = i >> 4, cc = i & 15;
        if (m < valid) {
            nt4 val = *(const nt4*)(hid + m * 128 + ((cc ^ (m & 15)) << 3));
            __builtin_nontemporal_store(val, (nt4*)perm + ((size_t)(e0 + m)) * 16 + cc);
        }
    }
}

// ---------------------------------------------------------------------------
// FUSED gather: perm rows are 256B = [batch0 128B][batch1 128B]. One pass
// accumulates both batches for node n (u-run contiguous + v-list indirect).
// perm reads are non-temporal (read-once stream).
// ---------------------------------------------------------------------------
#define ACCUM8(q) { union { u32 u; float f; } xx;                         \
    xx.u = (q).x << 16;          a0 += xx.f;                              \
    xx.u = (q).x & 0xffff0000u;  a1 += xx.f;                              \
    xx.u = (q).y << 16;          a2 += xx.f;                              \
    xx.u = (q).y & 0xffff0000u;  a3 += xx.f;                              \
    xx.u = (q).z << 16;          a4 += xx.f;                              \
    xx.u = (q).z & 0xffff0000u;  a5 += xx.f;                              \
    xx.u = (q).w << 16;          a6 += xx.f;                              \
    xx.u = (q).w & 0xffff0000u;  a7 += xx.f; }

__global__ __launch_bounds__(256) void gather4_kernel(
    const u32* __restrict__ perm32, const int* __restrict__ uoff,
    const int* __restrict__ voff, const int* __restrict__ vmap,
    float* __restrict__ out)
{
    const int t = threadIdx.x, wave = t >> 6, l = t & 63;
    const int n = blockIdx.x * 4 + wave;
    const int ub = uoff[n], ucnt = uoff[n + 1] - ub;
    const int vb = voff[n], vcnt = voff[n + 1] - vb;
    if ((ucnt | vcnt) == 0) return;
    const int sg = l >> 4, c16 = l & 15;   // 4 slots/group, 16B col in 256B row
    float a0=0.f,a1=0.f,a2=0.f,a3=0.f,a4=0.f,a5=0.f,a6=0.f,a7=0.f;

    for (int j0 = 0; j0 < ucnt; j0 += 8) {
        int jA = j0 + sg, jB = j0 + 4 + sg;
        nt4 qA = __builtin_nontemporal_load(
            (const nt4*)(perm32 + (size_t)(ub + min(jA, ucnt - 1)) * 64 + c16 * 4));
        nt4 qB = __builtin_nontemporal_load(
            (const nt4*)(perm32 + (size_t)(ub + min(jB, ucnt - 1)) * 64 + c16 * 4));
        if (jA < ucnt) ACCUM8(qA);
        if (jB < ucnt) ACCUM8(qB);
    }
    for (int j0 = 0; j0 < vcnt; j0 += 8) {
        int jA = j0 + sg, jB = j0 + 4 + sg;
        int pA = vmap[vb + min(jA, vcnt - 1)];
        int pB = vmap[vb + min(jB, vcnt - 1)];
        nt4 qA = __builtin_nontemporal_load(
            (const nt4*)(perm32 + (size_t)pA * 64 + c16 * 4));
        nt4 qB = __builtin_nontemporal_load(
            (const nt4*)(perm32 + (size_t)pB * 64 + c16 * 4));
        if (jA < vcnt) ACCUM8(qA);
        if (jB < vcnt) ACCUM8(qB);
    }

    a0 += __shfl_xor(a0, 16); a1 += __shfl_xor(a1, 16);
    a2 += __shfl_xor(a2, 16); a3 += __shfl_xor(a3, 16);
    a4 += __shfl_xor(a4, 16); a5 += __shfl_xor(a5, 16);
    a6 += __shfl_xor(a6, 16); a7 += __shfl_xor(a7, 16);
    a0 += __shfl_xor(a0, 32); a1 += __shfl_xor(a1, 32);
    a2 += __shfl_xor(a2, 32); a3 += __shfl_xor(a3, 32);
    a4 += __shfl_xor(a4, 32); a5 += __shfl_xor(a5, 32);
    a6 += __shfl_xor(a6, 32); a7 += __shfl_xor(a7, 32);

    if (l < 16) {   // lane = c16: 0..7 -> batch0 cols, 8..15 -> batch1 cols
        float* p = out + ((size_t)((l >> 3) * NN + n)) * 64 + (l & 7) * 8;
        float4 h0 = *(float4*)p, h1 = *(float4*)(p + 4);
        h0.x += a0; h0.y += a1; h0.z += a2; h0.w += a3;
        h1.x += a4; h1.y += a5; h1.z += a6; h1.w += a7;
        *(float4*)p = h0; *(float4*)(p + 4) = h1;
    }
}

// ---------------------------------------------------------------------------
extern "C" void kernel_launch(void* const* d_in, const int* in_sizes, int n_in,
                              void* d_out, int out_size, void* d_ws, size_t ws_size,
                              hipStream_t stream) {
    const float* x     = (const float*)d_in[0];
    const int*   edges = (const int*)d_in[1];
    const float* ew1   = (const float*)d_in[2];
    const float* eb1   = (const float*)d_in[3];
    const float* ew2   = (const float*)d_in[4];
    const float* eb2   = (const float*)d_in[5];
    const float* nw1   = (const float*)d_in[6];
    const float* nb1   = (const float*)d_in[7];
    const float* nw2   = (const float*)d_in[8];
    const float* nb2   = (const float*)d_in[9];
    const float* dw    = (const float*)d_in[10];
    const float* db    = (const float*)d_in[11];
    float* out = (float*)d_out;    // [BN][64]

    // Workspace layout (512B aligned)
    char* w = (char*)d_ws;
    size_t o = 0;
    auto take = [&](size_t bytes) { char* p = w + o; o = (o + bytes + 511) & ~(size_t)511; return p; };
    u16*   frag   = (u16*)  take(81920 * 2);                   // 160 KB
    float* bias2  = (float*)take(128 * 4);
    int*   curU   = (int*)  take((size_t)NN * 4);
    int*   curV   = (int*)  take((size_t)NN * 4);
    int*   uoff   = (int*)  take((size_t)(NN + 1) * 4);
    int*   voff   = (int*)  take((size_t)(NN + 1) * 4);
    int*   bsum2  = (int*)  take((size_t)2 * (NSB + 1) * 4);
    int*   boff2  = (int*)  take((size_t)2 * (NSB + 1) * 4);
    int*   vmap   = (int*)  take((size_t)NE * 4);              // 2 MB
    int2*  uv     = (int2*) take((size_t)NE * 8);              // 4 MB
    u16*   At     = (u16*)  take((size_t)BN * 256 * 2);        // 51.2 MB ([node][2][256])
    u16*   Ab     = (u16*)  take((size_t)BN * 256 * 2);        // 51.2 MB ([node][2][256])
    u16*   perm   = (u16*)  take((size_t)NE * 128 * 2);        // 128 MB (interleaved)
    (void)ws_size;

    // zero histograms (DMA memsets, replaces a dispatch)
    (void)hipMemsetAsync(curU, 0, (size_t)NN * 4, stream);
    (void)hipMemsetAsync(curV, 0, (size_t)NN * 4, stream);

    // weight prep || CSR histogram (independent work, one dispatch)
    weight_prep_hist<<<321 + (NE + 255) / 256, 256, 0, stream>>>(
        ew1, nw1, ew2, nw2, dw, db, eb2, nb2, edges, curU, curV, frag, bias2);

    // node+edge per-node tables || scan_pass1 (both axes)
    node_mlp_kernel<<<NODE_NB + 2 * NSB, 256, 0, stream>>>(
        x, nb1, eb1, bias2, frag, At, Ab, out, curU, curV, bsum2);

    scan_pass2d<<<dim3(1, 2), 256, 0, stream>>>(bsum2, boff2);
    scan_pass3d<<<dim3(NSB, 2), 256, 0, stream>>>(curU, curV, boff2, uoff, voff);
    csr_fill2<<<(NE + 255) / 256, 256, 0, stream>>>(edges, curU, curV, uv, vmap);

    // edge MLP both batches -> interleaved perm rows (nt stores)
    edge_emb3_kernel<<<(NE + 63) / 64, 256, 0, stream>>>(At, Ab, uv, bias2, frag, perm);

    // one gather for both batches (nt perm reads)
    gather4_kernel<<<NN / 4, 256, 0, stream>>>((const u32*)perm, uoff, voff, vmap, out);
}

// Round 17
// 405.053 us; speedup vs baseline: 1.1020x; 1.0059x over previous
//
#include <hip/hip_runtime.h>
#include <hip/hip_bf16.h>

// Problem constants
#define BB   2
#define NN   50000
#define BN   100000     // B*N
#define NE   500000
#define NSB  196        // scan blocks = ceil(NN/256)
#define NODE_NB 1563    // ceil(BN/64)

using u16 = unsigned short;
using u32 = unsigned int;
typedef __attribute__((ext_vector_type(8))) short short8;      // 8 x bf16/f16 bits
typedef __attribute__((ext_vector_type(8))) _Float16 half8;    // 8 x f16 (4 VGPRs)
typedef __attribute__((ext_vector_type(4))) float f32x4;       // MFMA accumulator
typedef __attribute__((ext_vector_type(4))) unsigned int nt4;  // native 16B vector (nt st)

__device__ __forceinline__ u16 f2bf(float f) {   // RNE f32 -> bf16 (finite inputs)
    union { float f; u32 u; } w; w.f = f;
    return (u16)((w.u + 0x7fffu + ((w.u >> 16) & 1u)) >> 16);
}
__device__ __forceinline__ u16 f2h(float f) {    // RNE f32 -> f16
    _Float16 h = (_Float16)f; u16 u; __builtin_memcpy(&u, &h, 2); return u;
}

#if defined(__has_builtin)
#if __has_builtin(__builtin_amdgcn_cvt_pk_bf16_f32)
#define HAVE_CVTPK 1
#endif
#if __has_builtin(__builtin_amdgcn_cvt_pkrtz)
#define HAVE_PKRTZ 1
#endif
#endif

__device__ __forceinline__ u32 pack_bf(float lo, float hi) {
#ifdef HAVE_CVTPK
    auto r = __builtin_amdgcn_cvt_pk_bf16_f32(lo, hi);
    u32 out; __builtin_memcpy(&out, &r, sizeof(out));
    return out;
#else
    return ((u32)f2bf(hi) << 16) | (u32)f2bf(lo);
#endif
}

__device__ __forceinline__ u32 pack_h2(float lo, float hi) {
#ifdef HAVE_PKRTZ
    auto r = __builtin_amdgcn_cvt_pkrtz(lo, hi);
    u32 out; __builtin_memcpy(&out, &r, sizeof(out));
    return out;
#else
    return ((u32)f2h(hi) << 16) | (u32)f2h(lo);
#endif
}

__device__ __forceinline__ u32 pk_add_h2(u32 a, u32 b) {
    u32 d; asm("v_pk_add_f16 %0, %1, %2" : "=v"(d) : "v"(a), "v"(b)); return d;
}
__device__ __forceinline__ u32 pk_relu_h2(u32 a) {
    u32 d, z = 0u;
    asm("v_pk_max_f16 %0, %1, %2" : "=v"(d) : "v"(a), "v"(z)); return d;
}
__device__ __forceinline__ half8 as_h8(short8 s) {
    half8 h; __builtin_memcpy(&h, &s, 16); return h;
}

// ---------------------------------------------------------------------------
// Weight prep (blocks 0..320) fused with CSR histogram (blocks 321..).
// frag regions (u16): w1e @0 ([16][4][64][8] bf16), w1n @32768 ([16][2][64][8]),
//                     w2e' @49152 ([4][8][64][8] f16), w2n' @65536 (bf16).
// ---------------------------------------------------------------------------
__global__ __launch_bounds__(256) void weight_prep_hist(
    const float* __restrict__ ew1, const float* __restrict__ nw1,
    const float* __restrict__ ew2, const float* __restrict__ nw2,
    const float* __restrict__ dw,  const float* __restrict__ db,
    const float* __restrict__ eb2, const float* __restrict__ nb2,
    const int* __restrict__ edges, int* __restrict__ curU, int* __restrict__ curV,
    u16* __restrict__ frag, float* __restrict__ bias2)
{
    int blk = blockIdx.x, t = threadIdx.x;
    if (blk >= 321) {                       // CSR histogram (independent work)
        int e = (blk - 321) * 256 + t;
        if (e < NE) {
            atomicAdd(&curU[edges[2*e]], 1);
            atomicAdd(&curV[edges[2*e+1]], 1);
        }
        return;
    }
    if (blk < 192) {
        int idx = blk * 256 + t;                 // 0..49151
        const float* src; int KB, local;
        if (idx < 32768) { local = idx;         src = ew1; KB = 4; }
        else             { local = idx - 32768; src = nw1; KB = 2; }
        int j = local & 7, l = (local >> 3) & 63, rest = local >> 9;
        int kblk = rest % KB, ntile = rest / KB;
        int n = ntile * 16 + (l & 15);
        int k = kblk * 32 + ((l >> 4) << 3) + j;
        frag[idx] = f2bf(src[k * 256 + n]);
    } else if (blk < 320) {
        int idx = (blk - 192) * 256 + t;         // 0..32767
        bool is_e = (idx < 16384);
        const float* src = is_e ? ew2 : nw2;
        int local = idx & 16383;
        int j = local & 7, l = (local >> 3) & 63, rest = local >> 9;
        int kblk = rest & 7, ntile = rest >> 3;
        int n = ntile * 16 + (l & 15);
        int k = kblk * 32 + ((l >> 4) << 3) + j;
        float s = 0.f;
        for (int jj = 0; jj < 128; ++jj) s = fmaf(src[k * 128 + jj], dw[jj * 64 + n], s);
        frag[49152 + idx] = is_e ? f2h(s) : f2bf(s);
    } else if (t < 128) {
        int d = t & 63;
        const float* bsrc = (t >= 64) ? nb2 : eb2;
        float s = 0.f;
        #pragma unroll 4
        for (int j = 0; j < 128; ++j) s = fmaf(bsrc[j], dw[j * 64 + d], s);
        if (t >= 64) bias2[64 + d] = s + db[d];
        else         bias2[d] = s;
    }
}

// ---------------------------------------------------------------------------
// scan passes 2/3 (y = 0 -> U, y = 1 -> V)
// ---------------------------------------------------------------------------
__global__ __launch_bounds__(256) void scan_pass2d(const int* __restrict__ bsum2,
                                                   int* __restrict__ boff2) {
    __shared__ int s[256];
    const int t = threadIdx.x;
    const int base = blockIdx.y * (NSB + 1);
    s[t] = (t < NSB) ? bsum2[base + t] : 0;
    __syncthreads();
    for (int d = 1; d < 256; d <<= 1) {
        int v = (t >= d) ? s[t - d] : 0;
        __syncthreads();
        s[t] += v;
        __syncthreads();
    }
    if (t <= NSB) boff2[base + t] = (t == 0) ? 0 : s[t - 1];
}

__global__ __launch_bounds__(256) void scan_pass3d(int* __restrict__ curU,
                                                   int* __restrict__ curV,
                                                   const int* __restrict__ boff2,
                                                   int* __restrict__ uoff,
                                                   int* __restrict__ voff) {
    __shared__ int s[256];
    const int t = threadIdx.x;
    int* cursor = blockIdx.y ? curV : curU;
    int* off    = blockIdx.y ? voff : uoff;
    const int base = blockIdx.y * (NSB + 1);
    int i = blockIdx.x * 256 + t;
    int v = (i < NN) ? cursor[i] : 0;
    s[t] = v;
    __syncthreads();
    for (int d = 1; d < 256; d <<= 1) {
        int p = (t >= d) ? s[t - d] : 0;
        __syncthreads();
        s[t] += p;
        __syncthreads();
    }
    int excl = boff2[base + blockIdx.x] + s[t] - v;
    if (i < NN) { off[i] = excl; cursor[i] = excl; }
    if (i == NN - 1) off[NN] = excl + v;
}

// ---------------------------------------------------------------------------
// Fused CSR fill: u-slot (uv row + slot id) and v-slot (vmap -> u-slot).
// ---------------------------------------------------------------------------
__global__ __launch_bounds__(256) void csr_fill2(const int* __restrict__ edges,
                                                 int* __restrict__ curU,
                                                 int* __restrict__ curV,
                                                 int2* __restrict__ uv,
                                                 int* __restrict__ vmap) {
    int e = blockIdx.x * 256 + threadIdx.x;
    if (e < NE) {
        int u = edges[2*e], v = edges[2*e+1];
        int s0 = atomicAdd(&curU[u], 1);
        uv[s0] = make_int2(u, v);
        int s1 = atomicAdd(&curV[v], 1);
        vmap[s1] = s0;
    }
}

// ---------------------------------------------------------------------------
// Node MLP (dw-fused) + edge-MLP per-node halves At/Ab for ALL BN rows.
// At/Ab layout is BATCH-INTERLEAVED: [node][batch][256] f16, so per edge the
// two batches' rows form one contiguous 512B region (halves the random-access
// count in edge_emb3). 24 KB LDS; hidden dim in two 128-wide halves. Also
// absorbs scan_pass1 (blocks >= NODE_NB).
// ---------------------------------------------------------------------------
__global__ __launch_bounds__(256) void node_mlp_kernel(
    const float* __restrict__ x, const float* __restrict__ nb1,
    const float* __restrict__ eb1, const float* __restrict__ bias2,
    const u16* __restrict__ frag,
    u16* __restrict__ At, u16* __restrict__ Ab, float* __restrict__ out,
    const int* __restrict__ curU, const int* __restrict__ curV,
    int* __restrict__ bsum2)
{
    __shared__ u16 xs[64 * 64];     // 8 KB, 8 chunks/row, swizzle mask 7
    __shared__ u16 hid[64 * 128];   // 16 KB, 16 chunks/row, swizzle mask 15
    const int t = threadIdx.x;

    if (blockIdx.x >= NODE_NB) {    // fused scan_pass1 for U and V histograms
        int sb = blockIdx.x - NODE_NB;       // 0..2*NSB-1
        int y = sb / NSB, xi = sb - y * NSB;
        const int* cursor = y ? curV : curU;
        int* s = (int*)xs;
        int i = xi * 256 + t;
        s[t] = (i < NN) ? cursor[i] : 0;
        __syncthreads();
        for (int d = 128; d > 0; d >>= 1) {
            if (t < d) s[t] += s[t + d];
            __syncthreads();
        }
        if (t == 0) bsum2[y * (NSB + 1) + xi] = s[0];
        return;
    }

    const int wave = t >> 6, l = t & 63, lane15 = l & 15, quad = l >> 4;
    const int r0 = blockIdx.x * 64;
    const int valid = min(64, BN - r0);

    // stage + convert x -> xs (bf16)
    #pragma unroll
    for (int it = 0; it < 4; ++it) {
        int i = t + it * 256;          // 0..1023
        int m = i >> 4, c4 = i & 15;   // row, float4-col (8B half-chunk)
        int row = min(r0 + m, BN - 1);
        float4 g = ((const float4*)x)[(size_t)row * 16 + c4];
        uint2 q = make_uint2(pack_bf(g.x, g.y), pack_bf(g.z, g.w));
        int chunk = c4 >> 1;
        *(uint2*)(xs + m * 64 + ((chunk ^ (m & 7)) << 3) + (c4 & 1) * 4) = q;
    }
    __syncthreads();

    // Node MLP: GEMM1 in two hidden halves, GEMM2 accumulates across halves.
    f32x4 acc2[4];
    #pragma unroll
    for (int mt = 0; mt < 4; ++mt) acc2[mt] = f32x4{0.f,0.f,0.f,0.f};
    const u16* w1n = frag + 32768;   // [16 ntile][2 kblk][64][8]
    const u16* w2n = frag + 65536;   // [4 ntile][8 kblk][64][8]
    #pragma unroll
    for (int H = 0; H < 2; ++H) {
        f32x4 acc1[2][4];
        #pragma unroll
        for (int i = 0; i < 2; ++i)
            #pragma unroll
            for (int mt = 0; mt < 4; ++mt) acc1[i][mt] = f32x4{0.f,0.f,0.f,0.f};
        #pragma unroll
        for (int kblk = 0; kblk < 2; ++kblk) {
            short8 bf[4], af[2];
            int chunk = kblk * 4 + quad;
            #pragma unroll
            for (int mt = 0; mt < 4; ++mt) {
                int row = mt*16 + lane15;
                bf[mt] = *(const short8*)(xs + row * 64 + ((chunk ^ (row & 7)) << 3));
            }
            #pragma unroll
            for (int i = 0; i < 2; ++i)
                af[i] = *(const short8*)(w1n + (((H*8 + wave*2 + i)*2 + kblk)*64 + l) * 8);
            #pragma unroll
            for (int i = 0; i < 2; ++i)
                #pragma unroll
                for (int mt = 0; mt < 4; ++mt)
                    acc1[i][mt] = __builtin_amdgcn_mfma_f32_16x16x32_bf16(af[i], bf[mt], acc1[i][mt], 0, 0, 0);
        }
        // epilogue: relu+bias -> bf16 hid half (cols [H*128, H*128+128))
        #pragma unroll
        for (int i = 0; i < 2; ++i) {
            int ntl = wave*2 + i;                  // local col-tile 0..7
            int n0 = (H*8 + ntl)*16 + quad*4;      // global hidden col
            int c16 = ntl*2 + (quad >> 1);         // local 16B chunk 0..15
            float4 bv = *(const float4*)(nb1 + n0);
            #pragma unroll
            for (int mt = 0; mt < 4; ++mt) {
                int row = mt*16 + lane15;
                uint2 q = make_uint2(
                    pack_bf(fmaxf(acc1[i][mt][0] + bv.x, 0.f), fmaxf(acc1[i][mt][1] + bv.y, 0.f)),
                    pack_bf(fmaxf(acc1[i][mt][2] + bv.z, 0.f), fmaxf(acc1[i][mt][3] + bv.w, 0.f)));
                *(uint2*)(hid + row * 128 + ((c16 ^ (row & 15)) << 3) + (quad & 1) * 4) = q;
            }
        }
        __syncthreads();
        // GEMM2 partial over this K-half
        #pragma unroll
        for (int kb = 0; kb < 4; ++kb) {
            short8 bf[4], af;
            int chunk = kb * 4 + quad;
            #pragma unroll
            for (int mt = 0; mt < 4; ++mt) {
                int row = mt*16 + lane15;
                bf[mt] = *(const short8*)(hid + row * 128 + ((chunk ^ (row & 15)) << 3));
            }
            af = *(const short8*)(w2n + ((wave*8 + H*4 + kb)*64 + l) * 8);
            #pragma unroll
            for (int mt = 0; mt < 4; ++mt)
                acc2[mt] = __builtin_amdgcn_mfma_f32_16x16x32_bf16(af, bf[mt], acc2[mt], 0, 0, 0);
        }
        __syncthreads();   // hid reusable (next half / edge phase)
    }
    {   // node output store (f32)
        int n0 = wave*16 + quad*4;
        float4 bv = *(const float4*)(bias2 + 64 + n0);
        #pragma unroll
        for (int mt = 0; mt < 4; ++mt) {
            int m = mt*16 + lane15;
            if (m < valid) {
                float4 o;
                o.x = acc2[mt][0] + bv.x; o.y = acc2[mt][1] + bv.y;
                o.z = acc2[mt][2] + bv.z; o.w = acc2[mt][3] + bv.w;
                *(float4*)(out + (size_t)(r0 + m) * 64 + n0) = o;
            }
        }
    }

    // Edge per-node halves: T=0 -> At (+eb1), T=1 -> Ab; each in 2 hidden halves.
    // Store to batch-interleaved layout: dst row = (node*2 + batch).
    const u16* w1e = frag;   // [16 ntile][4 kblk][64][8]; kblk 0-1 = top, 2-3 = bot
    #pragma unroll
    for (int T = 0; T < 2; ++T) {
        u16* dst = T ? Ab : At;
        #pragma unroll
        for (int H = 0; H < 2; ++H) {
            f32x4 acc[2][4];
            #pragma unroll
            for (int i = 0; i < 2; ++i)
                #pragma unroll
                for (int mt = 0; mt < 4; ++mt) acc[i][mt] = f32x4{0.f,0.f,0.f,0.f};
            #pragma unroll
            for (int kblk = 0; kblk < 2; ++kblk) {
                short8 bf[4], af[2];
                int chunk = kblk * 4 + quad;
                #pragma unroll
                for (int mt = 0; mt < 4; ++mt) {
                    int row = mt*16 + lane15;
                    bf[mt] = *(const short8*)(xs + row * 64 + ((chunk ^ (row & 7)) << 3));
                }
                #pragma unroll
                for (int i = 0; i < 2; ++i)
                    af[i] = *(const short8*)(w1e + (((H*8 + wave*2 + i)*4 + T*2 + kblk)*64 + l) * 8);
                #pragma unroll
                for (int i = 0; i < 2; ++i)
                    #pragma unroll
                    for (int mt = 0; mt < 4; ++mt)
                        acc[i][mt] = __builtin_amdgcn_mfma_f32_16x16x32_bf16(af[i], bf[mt], acc[i][mt], 0, 0, 0);
            }
            // epilogue -> f16 hid half
            #pragma unroll
            for (int i = 0; i < 2; ++i) {
                int ntl = wave*2 + i;
                int n0 = (H*8 + ntl)*16 + quad*4;
                int c16 = ntl*2 + (quad >> 1);
                float4 bv;
                if (T == 0) bv = *(const float4*)(eb1 + n0);
                else        bv = make_float4(0.f, 0.f, 0.f, 0.f);
                #pragma unroll
                for (int mt = 0; mt < 4; ++mt) {
                    int row = mt*16 + lane15;
                    uint2 q = make_uint2(
                        pack_h2(acc[i][mt][0] + bv.x, acc[i][mt][1] + bv.y),
                        pack_h2(acc[i][mt][2] + bv.z, acc[i][mt][3] + bv.w));
                    *(uint2*)(hid + row * 128 + ((c16 ^ (row & 15)) << 3) + (quad & 1) * 4) = q;
                }
            }
            __syncthreads();
            // store half-rows (256B contiguous per (row,H)) at interleaved slot
            #pragma unroll
            for (int it = 0; it < 4; ++it) {
                int i = t + it * 256;          // 0..1023
                int m = i >> 4, c = i & 15;
                if (m < valid) {
                    int row = r0 + m;                    // 0..BN-1
                    int bb  = row >= NN;                 // batch
                    int n   = bb ? row - NN : row;       // node
                    ((uint4*)dst)[((size_t)(n * 2 + bb)) * 32 + H*16 + c] =
                        *(const uint4*)(hid + m * 128 + ((c ^ (m & 15)) << 3));
                }
            }
            __syncthreads();   // hid reuse next (T,H)
        }
    }
}

// ---------------------------------------------------------------------------
// Edge combine + GEMM2 over u-SORTED edges, BOTH batches per block (4-phase,
// reg-prefetch). At/Ab are batch-interleaved [node][2][256] f16: per edge the
// random gather is ONE contiguous 512B region per table. perm rows stored
// NON-TEMPORAL (protect At/Ab residency during emb3).
// One 256B interleaved perm row per edge ([batch0 128B][batch1 128B]).
// ---------------------------------------------------------------------------
__global__ __launch_bounds__(256) void edge_emb3_kernel(
    const u16* __restrict__ At, const u16* __restrict__ Ab,
    const int2* __restrict__ uv, const float* __restrict__ bias2,
    const u16* __restrict__ frag, u16* __restrict__ perm)
{
    __shared__ u16 hid[64 * 128];   // 16 KB f16, 16 chunks/row, mask 15
    __shared__ int us[64], vs[64];
    const int t = threadIdx.x;
    const int wave = t >> 6, l = t & 63, lane15 = l & 15, quad = l >> 4;
    const int e0 = blockIdx.x * 64;
    const int valid = min(64, NE - e0);

    if (t < 64) {
        int2 p = uv[min(e0 + t, NE - 1)];
        us[t] = p.x;
        vs[t] = p.y;
    }
    __syncthreads();

    // per-thread gather geometry: 4 (m,c) pairs; c fixed = t&15
    const int c = t & 15;
    const uint4* at4 = (const uint4*)At;
    const uint4* ab4 = (const uint4*)Ab;
    int  mrow[4]; u32 ubase[4], vbase[4];
    #pragma unroll
    for (int it = 0; it < 4; ++it) {
        int m = (t + it * 256) >> 4;
        mrow[it]  = m;
        ubase[it] = (u32)us[m] * 64;   // node's 1KB region, uint4 units
        vbase[it] = (u32)vs[m] * 64;
    }

    // prologue: phase 0 (b=0, half=0) gather into registers
    uint4 pa[4], pb[4];
    #pragma unroll
    for (int it = 0; it < 4; ++it) {
        pa[it] = at4[(size_t)ubase[it] + c];
        pb[it] = ab4[(size_t)vbase[it] + c];
    }

    const u16* w2 = frag + 49152;    // [4 ntile][8 kblk][64][8] f16, ntile = wave
    f32x4 accB[2][4];
    #pragma unroll
    for (int b = 0; b < 2; ++b)
        #pragma unroll
        for (int mt = 0; mt < 4; ++mt) accB[b][mt] = f32x4{0.f,0.f,0.f,0.f};

    #pragma unroll
    for (int p = 0; p < 4; ++p) {
        const int b = p >> 1, half = p & 1;
        // combine from regs -> LDS
        #pragma unroll
        for (int it = 0; it < 4; ++it) {
            uint4 r;
            r.x = pk_relu_h2(pk_add_h2(pa[it].x, pb[it].x));
            r.y = pk_relu_h2(pk_add_h2(pa[it].y, pb[it].y));
            r.z = pk_relu_h2(pk_add_h2(pa[it].z, pb[it].z));
            r.w = pk_relu_h2(pk_add_h2(pa[it].w, pb[it].w));
            int m = mrow[it];
            *(uint4*)(hid + m * 128 + ((c ^ (m & 15)) << 3)) = r;
        }
        // issue next phase's gather (stays in flight under the MFMA below);
        // offset within node region: batch*32 + half*16 (uint4 units)
        if (p < 3) {
            const u32 noff = (u32)((((p + 1) >> 1) << 5) + (((p + 1) & 1) << 4));
            #pragma unroll
            for (int it = 0; it < 4; ++it) {
                pa[it] = at4[(size_t)ubase[it] + noff + c];
                pb[it] = ab4[(size_t)vbase[it] + noff + c];
            }
        }
        __syncthreads();
        // GEMM2^T quarter: N=64, K=128 (this half), f16 MFMA
        #pragma unroll
        for (int kb = 0; kb < 4; ++kb) {
            short8 bf[4], af;
            int chunk = kb * 4 + quad;
            #pragma unroll
            for (int mt = 0; mt < 4; ++mt) {
                int row = mt*16 + lane15;
                bf[mt] = *(const short8*)(hid + row * 128 + ((chunk ^ (row & 15)) << 3));
            }
            af = *(const short8*)(w2 + ((wave*8 + half*4 + kb)*64 + l) * 8);
            #pragma unroll
            for (int mt = 0; mt < 4; ++mt)
                accB[b][mt] = __builtin_amdgcn_mfma_f32_16x16x32_f16(as_h8(af), as_h8(bf[mt]), accB[b][mt], 0, 0, 0);
        }
        __syncthreads();   // hid reusable
    }

    {   // epilogue: both batches' bf16 rows into hid (256B/edge, mask 15)
        int n0 = wave*16 + quad*4;
        float4 bv = *(const float4*)(bias2 + n0);
        #pragma unroll
        for (int b = 0; b < 2; ++b) {
            int cc = b*8 + wave*2 + (quad >> 1);   // 16B chunk 0..15
            #pragma unroll
            for (int mt = 0; mt < 4; ++mt) {
                int m = mt*16 + lane15;
                uint2 q = make_uint2(
                    pack_bf(accB[b][mt][0] + bv.x, accB[b][mt][1] + bv.y),
                    pack_bf(accB[b][mt][2] + bv.z, accB[b][mt][3] + bv.w));
                *(uint2*)(hid + m * 128 + ((cc ^ (m & 15)) << 3) + (quad & 1) * 4) = q;
            }
        }
    }
    __syncthreads();

    // store: one 256B interleaved row per edge, NON-TEMPORAL
    #pragma unroll
    for (int it = 0; it < 4; ++it) {
        int i = t + it * 256;          // 0..1023
        int m = i >> 4, cc = i & 15;
        if (m < valid) {
            nt4 val = *(const nt4*)(hid + m * 128 + ((cc ^ (m & 15)) << 3));
            __builtin_nontemporal_store(val, (nt4*)perm + ((size_t)(e0 + m)) * 16 + cc);
        }
    }
}

// ---------------------------------------------------------------------------
// FUSED gather: perm rows are 256B = [batch0 128B][batch1 128B]. One pass
// accumulates both batches for node n (u-run contiguous + v-list indirect).
// PLAIN loads: the u-pass read allocates perm rows in L3 so the later v-pass
// read of the same row can hit (nt loads measurably forfeited this).
// ---------------------------------------------------------------------------
#define ACCUM8(q) { union { u32 u; float f; } xx;                         \
    xx.u = (q).x << 16;          a0 += xx.f;                              \
    xx.u = (q).x & 0xffff0000u;  a1 += xx.f;                              \
    xx.u = (q).y << 16;          a2 += xx.f;                              \
    xx.u = (q).y & 0xffff0000u;  a3 += xx.f;                              \
    xx.u = (q).z << 16;          a4 += xx.f;                              \
    xx.u = (q).z & 0xffff0000u;  a5 += xx.f;                              \
    xx.u = (q).w << 16;          a6 += xx.f;                              \
    xx.u = (q).w & 0xffff0000u;  a7 += xx.f; }

__global__ __launch_bounds__(256) void gather4_kernel(
    const u32* __restrict__ perm32, const int* __restrict__ uoff,
    const int* __restrict__ voff, const int* __restrict__ vmap,
    float* __restrict__ out)
{
    const int t = threadIdx.x, wave = t >> 6, l = t & 63;
    const int n = blockIdx.x * 4 + wave;
    const int ub = uoff[n], ucnt = uoff[n + 1] - ub;
    const int vb = voff[n], vcnt = voff[n + 1] - vb;
    if ((ucnt | vcnt) == 0) return;
    const int sg = l >> 4, c16 = l & 15;   // 4 slots/group, 16B col in 256B row
    float a0=0.f,a1=0.f,a2=0.f,a3=0.f,a4=0.f,a5=0.f,a6=0.f,a7=0.f;

    for (int j0 = 0; j0 < ucnt; j0 += 8) {
        int jA = j0 + sg, jB = j0 + 4 + sg;
        uint4 qA = *(const uint4*)(perm32 + (size_t)(ub + min(jA, ucnt - 1)) * 64 + c16 * 4);
        uint4 qB = *(const uint4*)(perm32 + (size_t)(ub + min(jB, ucnt - 1)) * 64 + c16 * 4);
        if (jA < ucnt) ACCUM8(qA);
        if (jB < ucnt) ACCUM8(qB);
    }
    for (int j0 = 0; j0 < vcnt; j0 += 8) {
        int jA = j0 + sg, jB = j0 + 4 + sg;
        int pA = vmap[vb + min(jA, vcnt - 1)];
        int pB = vmap[vb + min(jB, vcnt - 1)];
        uint4 qA = *(const uint4*)(perm32 + (size_t)pA * 64 + c16 * 4);
        uint4 qB = *(const uint4*)(perm32 + (size_t)pB * 64 + c16 * 4);
        if (jA < vcnt) ACCUM8(qA);
        if (jB < vcnt) ACCUM8(qB);
    }

    a0 += __shfl_xor(a0, 16); a1 += __shfl_xor(a1, 16);
    a2 += __shfl_xor(a2, 16); a3 += __shfl_xor(a3, 16);
    a4 += __shfl_xor(a4, 16); a5 += __shfl_xor(a5, 16);
    a6 += __shfl_xor(a6, 16); a7 += __shfl_xor(a7, 16);
    a0 += __shfl_xor(a0, 32); a1 += __shfl_xor(a1, 32);
    a2 += __shfl_xor(a2, 32); a3 += __shfl_xor(a3, 32);
    a4 += __shfl_xor(a4, 32); a5 += __shfl_xor(a5, 32);
    a6 += __shfl_xor(a6, 32); a7 += __shfl_xor(a7, 32);

    if (l < 16) {   // lane = c16: 0..7 -> batch0 cols, 8..15 -> batch1 cols
        float* p = out + ((size_t)((l >> 3) * NN + n)) * 64 + (l & 7) * 8;
        float4 h0 = *(float4*)p, h1 = *(float4*)(p + 4);
        h0.x += a0; h0.y += a1; h0.z += a2; h0.w += a3;
        h1.x += a4; h1.y += a5; h1.z += a6; h1.w += a7;
        *(float4*)p = h0; *(float4*)(p + 4) = h1;
    }
}

// ---------------------------------------------------------------------------
extern "C" void kernel_launch(void* const* d_in, const int* in_sizes, int n_in,
                              void* d_out, int out_size, void* d_ws, size_t ws_size,
                              hipStream_t stream) {
    const float* x     = (const float*)d_in[0];
    const int*   edges = (const int*)d_in[1];
    const float* ew1   = (const float*)d_in[2];
    const float* eb1   = (const float*)d_in[3];
    const float* ew2   = (const float*)d_in[4];
    const float* eb2   = (const float*)d_in[5];
    const float* nw1   = (const float*)d_in[6];
    const float* nb1   = (const float*)d_in[7];
    const float* nw2   = (const float*)d_in[8];
    const float* nb2   = (const float*)d_in[9];
    const float* dw    = (const float*)d_in[10];
    const float* db    = (const float*)d_in[11];
    float* out = (float*)d_out;    // [BN][64]

    // Workspace layout (512B aligned)
    char* w = (char*)d_ws;
    size_t o = 0;
    auto take = [&](size_t bytes) { char* p = w + o; o = (o + bytes + 511) & ~(size_t)511; return p; };
    u16*   frag   = (u16*)  take(81920 * 2);                   // 160 KB
    float* bias2  = (float*)take(128 * 4);
    int*   curU   = (int*)  take((size_t)NN * 4);
    int*   curV   = (int*)  take((size_t)NN * 4);
    int*   uoff   = (int*)  take((size_t)(NN + 1) * 4);
    int*   voff   = (int*)  take((size_t)(NN + 1) * 4);
    int*   bsum2  = (int*)  take((size_t)2 * (NSB + 1) * 4);
    int*   boff2  = (int*)  take((size_t)2 * (NSB + 1) * 4);
    int*   vmap   = (int*)  take((size_t)NE * 4);              // 2 MB
    int2*  uv     = (int2*) take((size_t)NE * 8);              // 4 MB
    u16*   At     = (u16*)  take((size_t)BN * 256 * 2);        // 51.2 MB ([node][2][256])
    u16*   Ab     = (u16*)  take((size_t)BN * 256 * 2);        // 51.2 MB ([node][2][256])
    u16*   perm   = (u16*)  take((size_t)NE * 128 * 2);        // 128 MB (interleaved)
    (void)ws_size;

    // zero histograms (DMA memsets, replaces a dispatch)
    (void)hipMemsetAsync(curU, 0, (size_t)NN * 4, stream);
    (void)hipMemsetAsync(curV, 0, (size_t)NN * 4, stream);

    // weight prep || CSR histogram (independent work, one dispatch)
    weight_prep_hist<<<321 + (NE + 255) / 256, 256, 0, stream>>>(
        ew1, nw1, ew2, nw2, dw, db, eb2, nb2, edges, curU, curV, frag, bias2);

    // node+edge per-node tables || scan_pass1 (both axes)
    node_mlp_kernel<<<NODE_NB + 2 * NSB, 256, 0, stream>>>(
        x, nb1, eb1, bias2, frag, At, Ab, out, curU, curV, bsum2);

    scan_pass2d<<<dim3(1, 2), 256, 0, stream>>>(bsum2, boff2);
    scan_pass3d<<<dim3(NSB, 2), 256, 0, stream>>>(curU, curV, boff2, uoff, voff);
    csr_fill2<<<(NE + 255) / 256, 256, 0, stream>>>(edges, curU, curV, uv, vmap);

    // edge MLP both batches -> interleaved perm rows (nt stores)
    edge_emb3_kernel<<<(NE + 63) / 64, 256, 0, stream>>>(At, Ab, uv, bias2, frag, perm);

    // one gather for both batches (plain perm reads -> L3 reuse u-pass->v-pass)
    gather4_kernel<<<NN / 4, 256, 0, stream>>>((const u32*)perm, uoff, voff, vmap, out);
}